// Round 1
// baseline (3283.320 us; speedup 1.0000x reference)
//
#include <hip/hip_runtime.h>
#include <cstdint>
#include <cstddef>

#define N_NODES   262144
#define NG        256
#define PP        1024
#define NE        4194304
#define FIN       128
#define HH        32
#define NC        10
#define OL        16
#define IL        96
#define NITER     3
#define ECHUNK    4096
#define NCHUNK    (NE/ECHUNK)   // 1024

// ---------------- degree + per-graph edge histogram (fused pass) ----------------
__global__ void k_hist(const int* __restrict__ ei, float* __restrict__ degf,
                       unsigned* __restrict__ hist) {
  __shared__ unsigned lh[NG];
  int t = threadIdx.x, b = blockIdx.x;
  lh[t] = 0;
  __syncthreads();
  int base = b * ECHUNK;
  for (int q = t; q < ECHUNK; q += 256) {
    int e = base + q;
    int s = ei[e], d = ei[NE + e];
    if (s != d) {
      atomicAdd(&lh[s >> 10], 1u);
      atomicAdd(&degf[d], 1.0f);
    }
  }
  __syncthreads();
  hist[b * NG + t] = lh[t];
}

__global__ void k_dis(const float* __restrict__ degf, float* __restrict__ dis) {
  int n = blockIdx.x * 256 + threadIdx.x;
  dis[n] = 1.0f / sqrtf(degf[n] + 1.0f);
}

// ---------------- scan: per-graph bases + per-chunk bases ----------------
__global__ void k_scan(const unsigned* __restrict__ hist, unsigned* __restrict__ cbase,
                       unsigned* __restrict__ gbase) {
  __shared__ unsigned sc[NG];
  int t = threadIdx.x;
  unsigned tot = 0;
  for (int ch = 0; ch < NCHUNK; ++ch) tot += hist[ch * NG + t];
  sc[t] = tot;
  __syncthreads();
  for (int off = 1; off < NG; off <<= 1) {
    unsigned v = (t >= off) ? sc[t - off] : 0u;
    __syncthreads();
    sc[t] += v;
    __syncthreads();
  }
  if (t == 0) gbase[0] = 0;
  gbase[t + 1] = sc[t];                 // inclusive
  unsigned acc = sc[t] - tot;           // exclusive
  for (int ch = 0; ch < NCHUNK; ++ch) {
    cbase[ch * NG + t] = acc;
    acc += hist[ch * NG + t];
  }
}

// ---------------- scatter edges into graph buckets ----------------
__global__ void k_scatter(const int* __restrict__ ei, const unsigned* __restrict__ cbase,
                          unsigned* __restrict__ epack) {
  __shared__ unsigned lcur[NG];
  int t = threadIdx.x, b = blockIdx.x;
  lcur[t] = cbase[b * NG + t];
  __syncthreads();
  int base = b * ECHUNK;
  for (int q = t; q < ECHUNK; q += 256) {
    int e = base + q;
    int s = ei[e], d = ei[NE + e];
    if (s != d) {
      int g = s >> 10;
      unsigned pos = atomicAdd(&lcur[g], 1u);
      epack[pos] = (unsigned)(s & 1023) | ((unsigned)(d & 1023) << 10);
    }
  }
}

// ---------------- per-graph counting sort by src offset, + CSR ptrs + weights ----------------
__global__ __launch_bounds__(256) void k_srcsort(const unsigned* __restrict__ epack,
                          const unsigned* __restrict__ gbase,
                          const float* __restrict__ dis,
                          unsigned* __restrict__ epack2, float* __restrict__ ew2,
                          unsigned* __restrict__ srcptr) {
  __shared__ unsigned shist[PP];
  __shared__ unsigned wsum[256];
  __shared__ unsigned cur[PP];
  int t = threadIdx.x, g = blockIdx.x;
  unsigned e0 = gbase[g], e1 = gbase[g + 1];
  for (int i = t; i < PP; i += 256) shist[i] = 0;
  __syncthreads();
  for (unsigned e = e0 + t; e < e1; e += 256)
    atomicAdd(&shist[epack[e] & 1023], 1u);
  __syncthreads();
  unsigned h0 = shist[4 * t], h1 = shist[4 * t + 1], h2 = shist[4 * t + 2], h3 = shist[4 * t + 3];
  unsigned tsum = h0 + h1 + h2 + h3;
  wsum[t] = tsum;
  __syncthreads();
  for (int off = 1; off < 256; off <<= 1) {
    unsigned v = (t >= off) ? wsum[t - off] : 0u;
    __syncthreads();
    wsum[t] += v;
    __syncthreads();
  }
  unsigned excl = wsum[t] - tsum + e0;
  unsigned c0 = excl, c1 = c0 + h0, c2 = c1 + h1, c3 = c2 + h2;
  cur[4 * t] = c0; cur[4 * t + 1] = c1; cur[4 * t + 2] = c2; cur[4 * t + 3] = c3;
  unsigned* spg = srcptr + (size_t)g * (PP + 1);
  spg[4 * t] = c0; spg[4 * t + 1] = c1; spg[4 * t + 2] = c2; spg[4 * t + 3] = c3;
  if (t == 0) spg[PP] = e1;
  __syncthreads();
  const float* disg = dis + g * PP;
  for (unsigned e = e0 + t; e < e1; e += 256) {
    unsigned pk = epack[e];
    unsigned so = pk & 1023, dofs = (pk >> 10) & 1023;
    unsigned pos = atomicAdd(&cur[so], 1u);
    epack2[pos] = pk;
    ew2[pos] = disg[so] * disg[dofs];
  }
}

// ---------------- fp32 GEMM: out(N x 32) = xin(N x K, row stride ldx) @ W(K x 32) ----------------
__global__ __launch_bounds__(256) void k_gemm(const float* __restrict__ xin, int ldx, int K,
                                              const float* __restrict__ W,
                                              float* __restrict__ out) {
  __shared__ float Wt[32 * (FIN + 4)];
  int t = threadIdx.x, b = blockIdx.x;
  int stride = K + 4;
  for (int idx = t; idx < K * 32; idx += 256) {
    int k = idx >> 5, c = idx & 31;
    Wt[c * stride + k] = W[idx];
  }
  __syncthreads();
  int cg = t & 3, ng = t >> 2;
  int row0 = b * 512 + ng * 8;
  float acc[8][8];
#pragma unroll
  for (int r = 0; r < 8; ++r)
#pragma unroll
    for (int j = 0; j < 8; ++j) acc[r][j] = 0.f;
  for (int k4 = 0; k4 < (K >> 2); ++k4) {
    float4 xv[8];
#pragma unroll
    for (int r = 0; r < 8; ++r)
      xv[r] = *(const float4*)(xin + (size_t)(row0 + r) * ldx + k4 * 4);
    float4 wvv[8];
#pragma unroll
    for (int j = 0; j < 8; ++j)
      wvv[j] = *(const float4*)&Wt[(cg + 4 * j) * stride + k4 * 4];
#pragma unroll
    for (int j = 0; j < 8; ++j)
#pragma unroll
      for (int r = 0; r < 8; ++r)
        acc[r][j] += xv[r].x * wvv[j].x + xv[r].y * wvv[j].y + xv[r].z * wvv[j].z + xv[r].w * wvv[j].w;
  }
#pragma unroll
  for (int r = 0; r < 8; ++r)
#pragma unroll
    for (int j = 0; j < 8; ++j)
      out[(size_t)(row0 + r) * HH + cg + 4 * j] = acc[r][j];
}

// ---------------- aggregation: one block per (graph, 16-channel half) ----------------
__global__ __launch_bounds__(256) void k_agg(const float* __restrict__ hlin,
                                             const float* __restrict__ dis,
                                             const unsigned* __restrict__ epack2,
                                             const float* __restrict__ ew2,
                                             const unsigned* __restrict__ srcptr,
                                             const float* __restrict__ bias,
                                             int coloff,
                                             float* __restrict__ h) {
  __shared__ float agg[16 * PP];   // [c][k] : exactly 64 KiB
  int t = threadIdx.x;
  int g = blockIdx.x >> 1, half = blockIdx.x & 1;
  int c0 = half * 16;
  float hv[4][16];
  float d2[4];
  unsigned es[4], ee[4];
  const unsigned* sp = srcptr + (size_t)g * (PP + 1);
#pragma unroll
  for (int r = 0; r < 4; ++r) {
    int k = t + r * 256;
    const float* row = hlin + (size_t)(g * PP + k) * HH + c0;
#pragma unroll
    for (int cq = 0; cq < 4; ++cq) {
      float4 v = *(const float4*)(row + cq * 4);
      hv[r][cq * 4 + 0] = v.x; hv[r][cq * 4 + 1] = v.y;
      hv[r][cq * 4 + 2] = v.z; hv[r][cq * 4 + 3] = v.w;
    }
    float dv = dis[g * PP + k];
    d2[r] = dv * dv;
    es[r] = sp[k]; ee[r] = sp[k + 1];
  }
#pragma unroll
  for (int r = 0; r < 4; ++r) {
    int k = t + r * 256;
#pragma unroll
    for (int c = 0; c < 16; ++c)
      agg[c * PP + k] = hv[r][c] * d2[r];   // self-loop term deg^-1
  }
  __syncthreads();
  for (int r = 0; r < 4; ++r) {
    for (unsigned e = es[r]; e < ee[r]; ++e) {
      unsigned pk = epack2[e];
      unsigned dofs = (pk >> 10) & 1023;
      float w = ew2[e];
#pragma unroll
      for (int c = 0; c < 16; ++c)
        atomicAdd(&agg[c * PP + dofs], hv[r][c] * w);
    }
  }
  __syncthreads();
  float bl[16];
#pragma unroll
  for (int c = 0; c < 16; ++c) bl[c] = bias[c0 + c];
#pragma unroll
  for (int kb = 0; kb < 4; ++kb) {
    int k = t + kb * 256;
    float* orow = h + (size_t)(g * PP + k) * IL + coloff + c0;
#pragma unroll
    for (int c = 0; c < 16; ++c)
      orow[c] = tanhf(agg[c * PP + k] + bl[c]);
  }
}

// ---------------- per-graph column sums of h ----------------
__global__ void k_colsum(const float* __restrict__ h, float* __restrict__ colsum) {
  __shared__ float cs[IL];
  int t = threadIdx.x, g = blockIdx.x;
  if (t < IL) cs[t] = 0.f;
  __syncthreads();
  for (int idx = t; idx < PP * 24; idx += 256) {
    int k = idx / 24, i4 = idx % 24;
    float4 v = *(const float4*)(h + (size_t)(g * PP + k) * IL + i4 * 4);
    atomicAdd(&cs[i4 * 4 + 0], v.x);
    atomicAdd(&cs[i4 * 4 + 1], v.y);
    atomicAdd(&cs[i4 * 4 + 2], v.z);
    atomicAdd(&cs[i4 * 4 + 3], v.w);
  }
  __syncthreads();
  if (t < IL) colsum[g * IL + t] = cs[t];
}

// ---------------- per-graph stable descending sort by last channel (bitonic) ----------------
__global__ void k_sort(const float* __restrict__ h, unsigned* __restrict__ order) {
  __shared__ float key[PP];
  __shared__ unsigned sidx[PP];
  int t = threadIdx.x, g = blockIdx.x;
  for (int i = t; i < PP; i += 256) {
    key[i] = h[(size_t)(g * PP + i) * IL + (IL - 1)];
    sidx[i] = i;
  }
  __syncthreads();
  for (int sz = 2; sz <= PP; sz <<= 1) {
    for (int st = sz >> 1; st > 0; st >>= 1) {
      for (int q = t; q < PP / 2; q += 256) {
        int i = 2 * q - (q & (st - 1));
        int j = i + st;
        float ki = key[i], kj = key[j];
        unsigned ii = sidx[i], ij = sidx[j];
        // total order: descending key, ties -> ascending original index (stable argsort(-key))
        bool less_ji = (kj > ki) || (kj == ki && ij < ii);
        bool asc = ((i & sz) == 0);
        if (less_ji == asc) { key[i] = kj; key[j] = ki; sidx[i] = ij; sidx[j] = ii; }
      }
      __syncthreads();
    }
  }
  for (int i = t; i < PP; i += 256) order[g * PP + i] = sidx[i];
}

// ---------------- position encoding ----------------
__global__ void k_pe(float* __restrict__ pe) {
  int id = blockIdx.x * 256 + threadIdx.x;
  if (id >= PP * 48) return;
  int pos = id / 48, i = id % 48;
  float denom = powf(10000.0f, (2.0f * i) / 96.0f);
  float ang = (float)pos / denom;
  pe[pos * IL + 2 * i] = sinf(ang);
  pe[pos * IL + 2 * i + 1] = cosf(ang);
}

__global__ void k_pemean(const float* __restrict__ pe, float* __restrict__ pemean) {
  int t = threadIdx.x;
  if (t >= IL) return;
  float s = 0;
  for (int p = 0; p < PP; ++p) s += pe[p * IL + t];
  pemean[t] = s * (1.0f / PP);
}

// ---------------- capsule k-means routing, one block per graph ----------------
__global__ __launch_bounds__(256) void k_route(const float* __restrict__ h,
                                               const float* __restrict__ pe,
                                               const float* __restrict__ pemean,
                                               const float* __restrict__ colsum,
                                               const unsigned* __restrict__ order,
                                               const float* __restrict__ capsW,
                                               float* __restrict__ out) {
  __shared__ unsigned ord[PP];
  __shared__ float u_l[NC * IL];
  __shared__ float e_l[PP * 12];
  __shared__ float s_l[NC * IL];
  __shared__ float v_l[NC * OL];
  __shared__ float nrm_l[NC];
  __shared__ float gmax_l[NC], gsum_l[NC];
  __shared__ float wred[4][NC];
  int t = threadIdx.x, g = blockIdx.x;
  int lane = t & 63, wvi = t >> 6;
  for (int i = t; i < PP; i += 256) ord[i] = order[g * PP + i];
  if (t < IL) s_l[t] = colsum[g * IL + t] * (1.0f / PP) + pemean[t];   // m = mean_k hs
  __syncthreads();
  if (t < NC * OL) {
    int c = t >> 4, j = t & 15;
    const float* wr = capsW + (size_t)(c * OL + j) * IL;
    float a = 0;
    for (int i = 0; i < IL; ++i) a += wr[i] * s_l[i];
    v_l[t] = a;                                                        // v0 = mean priors
  }
  __syncthreads();
  const float* hg = h + (size_t)g * PP * IL;

  for (int it = 0; it < NITER; ++it) {
    if (t < NC) {
      float n2 = 0;
#pragma unroll
      for (int j = 0; j < OL; ++j) { float x = v_l[t * OL + j]; n2 += x * x; }
      nrm_l[t] = 1.0f / (sqrtf(n2) + 1e-12f);
    }
    __syncthreads();
    for (int idx = t; idx < NC * IL; idx += 256) {   // u[c][i] = caps_W^T vn
      int c = idx / IL, i = idx - c * IL;
      const float* wr = capsW + (size_t)c * OL * IL + i;
      float a = 0;
#pragma unroll
      for (int j = 0; j < OL; ++j) a += wr[j * IL] * v_l[c * OL + j];
      u_l[idx] = a * nrm_l[c];
    }
    __syncthreads();
    // ---- logits pass: logits[k][c] = (h[ord[k]] + pe[k]) . u_c ----
    float acc[4][NC];
#pragma unroll
    for (int r = 0; r < 4; ++r)
#pragma unroll
      for (int c = 0; c < NC; ++c) acc[r][c] = 0.f;
    const float* hb[4]; const float* pb[4];
#pragma unroll
    for (int r = 0; r < 4; ++r) {
      int k = t + r * 256;
      hb[r] = hg + (size_t)ord[k] * IL;
      pb[r] = pe + (size_t)k * IL;
    }
    for (int i4 = 0; i4 < 24; ++i4) {
      float4 hs4[4];
#pragma unroll
      for (int r = 0; r < 4; ++r) {
        float4 a = *(const float4*)(hb[r] + i4 * 4);
        float4 p = *(const float4*)(pb[r] + i4 * 4);
        hs4[r] = make_float4(a.x + p.x, a.y + p.y, a.z + p.z, a.w + p.w);
      }
#pragma unroll
      for (int c = 0; c < NC; ++c) {
        float4 u4 = *(const float4*)&u_l[c * IL + i4 * 4];
#pragma unroll
        for (int r = 0; r < 4; ++r)
          acc[r][c] += hs4[r].x * u4.x + hs4[r].y * u4.y + hs4[r].z * u4.z + hs4[r].w * u4.w;
      }
    }
    // ---- softmax over k (max, unnormalized exp, sum) ----
    float lmax[NC];
#pragma unroll
    for (int c = 0; c < NC; ++c)
      lmax[c] = fmaxf(fmaxf(acc[0][c], acc[1][c]), fmaxf(acc[2][c], acc[3][c]));
#pragma unroll
    for (int c = 0; c < NC; ++c)
      for (int m = 32; m >= 1; m >>= 1)
        lmax[c] = fmaxf(lmax[c], __shfl_xor(lmax[c], m, 64));
    if (lane == 0)
#pragma unroll
      for (int c = 0; c < NC; ++c) wred[wvi][c] = lmax[c];
    __syncthreads();
    if (t < NC) gmax_l[t] = fmaxf(fmaxf(wred[0][t], wred[1][t]), fmaxf(wred[2][t], wred[3][t]));
    __syncthreads();
    float lsum[NC];
#pragma unroll
    for (int c = 0; c < NC; ++c) lsum[c] = 0.f;
#pragma unroll
    for (int r = 0; r < 4; ++r) {
      int k = t + r * 256;
#pragma unroll
      for (int c = 0; c < NC; ++c) {
        float ev = __expf(acc[r][c] - gmax_l[c]);
        e_l[k * 12 + c] = ev;
        lsum[c] += ev;
      }
    }
#pragma unroll
    for (int c = 0; c < NC; ++c)
      for (int m = 32; m >= 1; m >>= 1)
        lsum[c] += __shfl_xor(lsum[c], m, 64);
    if (lane == 0)
#pragma unroll
      for (int c = 0; c < NC; ++c) wred[wvi][c] = lsum[c];
    __syncthreads();
    if (t < NC) gsum_l[t] = wred[0][t] + wred[1][t] + wred[2][t] + wred[3][t];
    for (int idx = t; idx < NC * IL; idx += 256) s_l[idx] = 0.f;
    __syncthreads();
    // ---- s-pass: s[c][i] = sum_k e[k][c] * hs[k][i]  (32 kstrips x 8 islices) ----
    int isl = t & 7, ks = t >> 3;
    float sl[NC][12];
#pragma unroll
    for (int c = 0; c < NC; ++c)
#pragma unroll
      for (int d = 0; d < 12; ++d) sl[c][d] = 0.f;
    for (int kk = 0; kk < 32; ++kk) {
      int k = ks + 32 * kk;
      int n = ord[k];
      const float* hr = hg + (size_t)n * IL + isl * 12;
      const float* pr = pe + (size_t)k * IL + isl * 12;
      float hv2[12];
#pragma unroll
      for (int q = 0; q < 3; ++q) {
        float4 a = *(const float4*)(hr + q * 4);
        float4 p = *(const float4*)(pr + q * 4);
        hv2[q * 4 + 0] = a.x + p.x; hv2[q * 4 + 1] = a.y + p.y;
        hv2[q * 4 + 2] = a.z + p.z; hv2[q * 4 + 3] = a.w + p.w;
      }
      float4 e0 = *(const float4*)&e_l[k * 12];
      float4 e1 = *(const float4*)&e_l[k * 12 + 4];
      float4 e2 = *(const float4*)&e_l[k * 12 + 8];
      float ev[NC] = {e0.x, e0.y, e0.z, e0.w, e1.x, e1.y, e1.z, e1.w, e2.x, e2.y};
#pragma unroll
      for (int c = 0; c < NC; ++c)
#pragma unroll
        for (int d = 0; d < 12; ++d)
          sl[c][d] += ev[c] * hv2[d];
    }
#pragma unroll
    for (int c = 0; c < NC; ++c)
#pragma unroll
      for (int d = 0; d < 12; ++d) {
        float x = sl[c][d];
        x += __shfl_xor(x, 8, 64);
        x += __shfl_xor(x, 16, 64);
        x += __shfl_xor(x, 32, 64);
        sl[c][d] = x;
      }
    if ((lane >> 3) == 0) {
#pragma unroll
      for (int c = 0; c < NC; ++c)
#pragma unroll
        for (int d = 0; d < 12; ++d)
          atomicAdd(&s_l[c * IL + isl * 12 + d], sl[c][d]);
    }
    __syncthreads();
    // ---- v = caps_W @ s / sumexp ----
    if (t < NC * OL) {
      int c = t >> 4, j = t & 15;
      const float* wr = capsW + (size_t)(c * OL + j) * IL;
      float a = 0;
      for (int i = 0; i < IL; ++i) a += wr[i] * s_l[c * IL + i];
      v_l[t] = a / gsum_l[c];
    }
    __syncthreads();
  }
  if (t < NC) {
    float n2 = 0;
#pragma unroll
    for (int j = 0; j < OL; ++j) { float x = v_l[t * OL + j]; n2 += x * x; }
    out[g * NC + t] = (n2 / (1.0f + n2)) * sqrtf(n2) / sqrtf(n2 + 1e-12f);
  }
}

extern "C" void kernel_launch(void* const* d_in, const int* in_sizes, int n_in,
                              void* d_out, int out_size, void* d_ws, size_t ws_size,
                              hipStream_t stream) {
  const float* x     = (const float*)d_in[0];
  const int*   ei    = (const int*)d_in[1];
  const float* W1    = (const float*)d_in[3];
  const float* b1    = (const float*)d_in[4];
  const float* W2    = (const float*)d_in[5];
  const float* b2    = (const float*)d_in[6];
  const float* W3    = (const float*)d_in[7];
  const float* b3    = (const float*)d_in[8];
  const float* capsW = (const float*)d_in[9];
  float* out = (float*)d_out;

  char* wp = (char*)d_ws;
  auto alloc = [&](size_t bytes) { char* p = wp; wp += (bytes + 255) & ~(size_t)255; return p; };
  float*    degf   = (float*)alloc((size_t)N_NODES * 4);
  float*    dis    = (float*)alloc((size_t)N_NODES * 4);
  float*    h      = (float*)alloc((size_t)N_NODES * IL * 4);
  float*    hlin   = (float*)alloc((size_t)N_NODES * HH * 4);
  unsigned* epack  = (unsigned*)alloc((size_t)NE * 4);
  unsigned* epack2 = (unsigned*)alloc((size_t)NE * 4);
  float*    ew2    = (float*)alloc((size_t)NE * 4);
  unsigned* hist   = (unsigned*)alloc((size_t)NCHUNK * NG * 4);
  unsigned* cbase  = (unsigned*)alloc((size_t)NCHUNK * NG * 4);
  unsigned* gbase  = (unsigned*)alloc((size_t)(NG + 1) * 4);
  unsigned* srcptr = (unsigned*)alloc((size_t)NG * (PP + 1) * 4);
  unsigned* order  = (unsigned*)alloc((size_t)NG * PP * 4);
  float*    colsum = (float*)alloc((size_t)NG * IL * 4);
  float*    pe     = (float*)alloc((size_t)PP * IL * 4);
  float*    pemean = (float*)alloc((size_t)IL * 4);

  hipMemsetAsync(degf, 0, (size_t)N_NODES * 4, stream);
  k_hist<<<NCHUNK, 256, 0, stream>>>(ei, degf, hist);
  k_dis<<<N_NODES / 256, 256, 0, stream>>>(degf, dis);
  k_scan<<<1, 256, 0, stream>>>(hist, cbase, gbase);
  k_scatter<<<NCHUNK, 256, 0, stream>>>(ei, cbase, epack);
  k_srcsort<<<NG, 256, 0, stream>>>(epack, gbase, dis, epack2, ew2, srcptr);

  k_gemm<<<N_NODES / 512, 256, 0, stream>>>(x, FIN, FIN, W1, hlin);
  k_agg<<<NG * 2, 256, 0, stream>>>(hlin, dis, epack2, ew2, srcptr, b1, 0, h);
  k_gemm<<<N_NODES / 512, 256, 0, stream>>>(h, IL, HH, W2, hlin);
  k_agg<<<NG * 2, 256, 0, stream>>>(hlin, dis, epack2, ew2, srcptr, b2, 32, h);
  k_gemm<<<N_NODES / 512, 256, 0, stream>>>(h + 32, IL, HH, W3, hlin);
  k_agg<<<NG * 2, 256, 0, stream>>>(hlin, dis, epack2, ew2, srcptr, b3, 64, h);

  k_colsum<<<NG, 256, 0, stream>>>(h, colsum);
  k_sort<<<NG, 256, 0, stream>>>(h, order);
  k_pe<<<(PP * 48) / 256, 256, 0, stream>>>(pe);
  k_pemean<<<1, 128, 0, stream>>>(pe, pemean);
  k_route<<<NG, 256, 0, stream>>>(h, pe, pemean, colsum, order, capsW, out);
}

// Round 2
// 3200.679 us; speedup vs baseline: 1.0258x; 1.0258x over previous
//
#include <hip/hip_runtime.h>
#include <cstdint>
#include <cstddef>

#define N_NODES   262144
#define NG        256
#define PP        1024
#define NE        4194304
#define FIN       128
#define HH        32
#define NC        10
#define OL        16
#define IL        96
#define NITER     3
#define ECHUNK    4096
#define NCHUNK    (NE/ECHUNK)   // 1024

// ---------------- degree + per-graph edge histogram (fused pass) ----------------
__global__ void k_hist(const int* __restrict__ ei, float* __restrict__ degf,
                       unsigned* __restrict__ hist) {
  __shared__ unsigned lh[NG];
  int t = threadIdx.x, b = blockIdx.x;
  lh[t] = 0;
  __syncthreads();
  int base = b * ECHUNK;
  for (int q = t; q < ECHUNK; q += 256) {
    int e = base + q;
    int s = ei[e], d = ei[NE + e];
    if (s != d) {
      atomicAdd(&lh[s >> 10], 1u);
      atomicAdd(&degf[d], 1.0f);
    }
  }
  __syncthreads();
  hist[b * NG + t] = lh[t];
}

__global__ void k_dis(const float* __restrict__ degf, float* __restrict__ dis) {
  int n = blockIdx.x * 256 + threadIdx.x;
  dis[n] = 1.0f / sqrtf(degf[n] + 1.0f);
}

// ---------------- scan: per-graph bases + per-chunk bases ----------------
__global__ void k_scan(const unsigned* __restrict__ hist, unsigned* __restrict__ cbase,
                       unsigned* __restrict__ gbase) {
  __shared__ unsigned sc[NG];
  int t = threadIdx.x;
  unsigned tot = 0;
  for (int ch = 0; ch < NCHUNK; ++ch) tot += hist[ch * NG + t];
  sc[t] = tot;
  __syncthreads();
  for (int off = 1; off < NG; off <<= 1) {
    unsigned v = (t >= off) ? sc[t - off] : 0u;
    __syncthreads();
    sc[t] += v;
    __syncthreads();
  }
  if (t == 0) gbase[0] = 0;
  gbase[t + 1] = sc[t];                 // inclusive
  unsigned acc = sc[t] - tot;           // exclusive
  for (int ch = 0; ch < NCHUNK; ++ch) {
    cbase[ch * NG + t] = acc;
    acc += hist[ch * NG + t];
  }
}

// ---------------- scatter edges into graph buckets ----------------
__global__ void k_scatter(const int* __restrict__ ei, const unsigned* __restrict__ cbase,
                          unsigned* __restrict__ epack) {
  __shared__ unsigned lcur[NG];
  int t = threadIdx.x, b = blockIdx.x;
  lcur[t] = cbase[b * NG + t];
  __syncthreads();
  int base = b * ECHUNK;
  for (int q = t; q < ECHUNK; q += 256) {
    int e = base + q;
    int s = ei[e], d = ei[NE + e];
    if (s != d) {
      int g = s >> 10;
      unsigned pos = atomicAdd(&lcur[g], 1u);
      epack[pos] = (unsigned)(s & 1023) | ((unsigned)(d & 1023) << 10);
    }
  }
}

// ---------------- fp32 GEMM: out(N x 32) = xin(N x K, row stride ldx) @ W(K x 32) ----------------
__global__ __launch_bounds__(256) void k_gemm(const float* __restrict__ xin, int ldx, int K,
                                              const float* __restrict__ W,
                                              float* __restrict__ out) {
  __shared__ float Wt[32 * (FIN + 4)];
  int t = threadIdx.x, b = blockIdx.x;
  int stride = K + 4;
  for (int idx = t; idx < K * 32; idx += 256) {
    int k = idx >> 5, c = idx & 31;
    Wt[c * stride + k] = W[idx];
  }
  __syncthreads();
  int cg = t & 3, ng = t >> 2;
  int row0 = b * 512 + ng * 8;
  float acc[8][8];
#pragma unroll
  for (int r = 0; r < 8; ++r)
#pragma unroll
    for (int j = 0; j < 8; ++j) acc[r][j] = 0.f;
  for (int k4 = 0; k4 < (K >> 2); ++k4) {
    float4 xv[8];
#pragma unroll
    for (int r = 0; r < 8; ++r)
      xv[r] = *(const float4*)(xin + (size_t)(row0 + r) * ldx + k4 * 4);
    float4 wvv[8];
#pragma unroll
    for (int j = 0; j < 8; ++j)
      wvv[j] = *(const float4*)&Wt[(cg + 4 * j) * stride + k4 * 4];
#pragma unroll
    for (int j = 0; j < 8; ++j)
#pragma unroll
      for (int r = 0; r < 8; ++r)
        acc[r][j] += xv[r].x * wvv[j].x + xv[r].y * wvv[j].y + xv[r].z * wvv[j].z + xv[r].w * wvv[j].w;
  }
#pragma unroll
  for (int r = 0; r < 8; ++r)
#pragma unroll
    for (int j = 0; j < 8; ++j)
      out[(size_t)(row0 + r) * HH + cg + 4 * j] = acc[r][j];
}

// ---------------- aggregation: edge-parallel, one block per (graph, 8-channel quarter) ----------
// Algebra: agg_ref[n] = dis[n] * sum_{e:dst=n} dis[src]*hlin[src] + dis[n]^2*hlin[n]
// Stage hs[c][k] = hlin[k][c]*dis[k]; edges add hs[c][src] with weight 1;
// epilogue: h = tanh(dis[n]*(agg[c][n] + hs[c][n]) + bias).
__global__ __launch_bounds__(256) void k_agg(const float* __restrict__ hlin,
                                             const float* __restrict__ dis,
                                             const unsigned* __restrict__ epack,
                                             const unsigned* __restrict__ gbase,
                                             const float* __restrict__ bias,
                                             int coloff,
                                             float* __restrict__ h) {
  __shared__ float hs[8 * PP];    // 32 KiB src values pre-scaled by dis[src]
  __shared__ float agg[8 * PP];   // 32 KiB accumulator
  int t = threadIdx.x;
  int g = blockIdx.x >> 2, q = blockIdx.x & 3;
  int c0 = q * 8;
  float dv[4];
#pragma unroll
  for (int r = 0; r < 4; ++r) {
    int k = t + r * 256;
    float d = dis[g * PP + k];
    dv[r] = d;
    const float* row = hlin + (size_t)(g * PP + k) * HH + c0;
    float4 a = *(const float4*)row;
    float4 b2 = *(const float4*)(row + 4);
    hs[0 * PP + k] = a.x * d;  hs[1 * PP + k] = a.y * d;
    hs[2 * PP + k] = a.z * d;  hs[3 * PP + k] = a.w * d;
    hs[4 * PP + k] = b2.x * d; hs[5 * PP + k] = b2.y * d;
    hs[6 * PP + k] = b2.z * d; hs[7 * PP + k] = b2.w * d;
#pragma unroll
    for (int c = 0; c < 8; ++c) agg[c * PP + k] = 0.f;
  }
  __syncthreads();
  unsigned e0 = gbase[g], e1 = gbase[g + 1];
  unsigned e = e0 + t;
  for (; e + 256 < e1; e += 512) {
    unsigned pk0 = epack[e];
    unsigned pk1 = epack[e + 256];
    unsigned so0 = pk0 & 1023, do0 = (pk0 >> 10) & 1023;
    unsigned so1 = pk1 & 1023, do1 = (pk1 >> 10) & 1023;
    float v0[8], v1[8];
#pragma unroll
    for (int c = 0; c < 8; ++c) v0[c] = hs[c * PP + so0];
#pragma unroll
    for (int c = 0; c < 8; ++c) v1[c] = hs[c * PP + so1];
#pragma unroll
    for (int c = 0; c < 8; ++c) atomicAdd(&agg[c * PP + do0], v0[c]);
#pragma unroll
    for (int c = 0; c < 8; ++c) atomicAdd(&agg[c * PP + do1], v1[c]);
  }
  if (e < e1) {
    unsigned pk0 = epack[e];
    unsigned so0 = pk0 & 1023, do0 = (pk0 >> 10) & 1023;
#pragma unroll
    for (int c = 0; c < 8; ++c) atomicAdd(&agg[c * PP + do0], hs[c * PP + so0]);
  }
  __syncthreads();
  float bl[8];
#pragma unroll
  for (int c = 0; c < 8; ++c) bl[c] = bias[c0 + c];
#pragma unroll
  for (int r = 0; r < 4; ++r) {
    int k = t + r * 256;
    float* orow = h + (size_t)(g * PP + k) * IL + coloff + c0;
#pragma unroll
    for (int c = 0; c < 8; ++c)
      orow[c] = tanhf(dv[r] * (agg[c * PP + k] + hs[c * PP + k]) + bl[c]);
  }
}

// ---------------- per-graph column sums of h ----------------
__global__ void k_colsum(const float* __restrict__ h, float* __restrict__ colsum) {
  __shared__ float cs[IL];
  int t = threadIdx.x, g = blockIdx.x;
  if (t < IL) cs[t] = 0.f;
  __syncthreads();
  for (int idx = t; idx < PP * 24; idx += 256) {
    int k = idx / 24, i4 = idx % 24;
    float4 v = *(const float4*)(h + (size_t)(g * PP + k) * IL + i4 * 4);
    atomicAdd(&cs[i4 * 4 + 0], v.x);
    atomicAdd(&cs[i4 * 4 + 1], v.y);
    atomicAdd(&cs[i4 * 4 + 2], v.z);
    atomicAdd(&cs[i4 * 4 + 3], v.w);
  }
  __syncthreads();
  if (t < IL) colsum[g * IL + t] = cs[t];
}

// ---------------- per-graph stable descending sort by last channel (bitonic) ----------------
__global__ void k_sort(const float* __restrict__ h, unsigned* __restrict__ order) {
  __shared__ float key[PP];
  __shared__ unsigned sidx[PP];
  int t = threadIdx.x, g = blockIdx.x;
  for (int i = t; i < PP; i += 256) {
    key[i] = h[(size_t)(g * PP + i) * IL + (IL - 1)];
    sidx[i] = i;
  }
  __syncthreads();
  for (int sz = 2; sz <= PP; sz <<= 1) {
    for (int st = sz >> 1; st > 0; st >>= 1) {
      for (int q = t; q < PP / 2; q += 256) {
        int i = 2 * q - (q & (st - 1));
        int j = i + st;
        float ki = key[i], kj = key[j];
        unsigned ii = sidx[i], ij = sidx[j];
        // total order: descending key, ties -> ascending original index (stable argsort(-key))
        bool less_ji = (kj > ki) || (kj == ki && ij < ii);
        bool asc = ((i & sz) == 0);
        if (less_ji == asc) { key[i] = kj; key[j] = ki; sidx[i] = ij; sidx[j] = ii; }
      }
      __syncthreads();
    }
  }
  for (int i = t; i < PP; i += 256) order[g * PP + i] = sidx[i];
}

// ---------------- position encoding ----------------
__global__ void k_pe(float* __restrict__ pe) {
  int id = blockIdx.x * 256 + threadIdx.x;
  if (id >= PP * 48) return;
  int pos = id / 48, i = id % 48;
  float denom = powf(10000.0f, (2.0f * i) / 96.0f);
  float ang = (float)pos / denom;
  pe[pos * IL + 2 * i] = sinf(ang);
  pe[pos * IL + 2 * i + 1] = cosf(ang);
}

__global__ void k_pemean(const float* __restrict__ pe, float* __restrict__ pemean) {
  int t = threadIdx.x;
  if (t >= IL) return;
  float s = 0;
  for (int p = 0; p < PP; ++p) s += pe[p * IL + t];
  pemean[t] = s * (1.0f / PP);
}

// ---------------- capsule k-means routing, one block per graph ----------------
__global__ __launch_bounds__(256) void k_route(const float* __restrict__ h,
                                               const float* __restrict__ pe,
                                               const float* __restrict__ pemean,
                                               const float* __restrict__ colsum,
                                               const unsigned* __restrict__ order,
                                               const float* __restrict__ capsW,
                                               float* __restrict__ out) {
  __shared__ unsigned ord[PP];
  __shared__ float u_l[NC * IL];
  __shared__ float e_l[PP * 12];
  __shared__ float s_l[NC * IL];
  __shared__ float v_l[NC * OL];
  __shared__ float nrm_l[NC];
  __shared__ float gmax_l[NC], gsum_l[NC];
  __shared__ float wred[4][NC];
  int t = threadIdx.x, g = blockIdx.x;
  int lane = t & 63, wvi = t >> 6;
  for (int i = t; i < PP; i += 256) ord[i] = order[g * PP + i];
  if (t < IL) s_l[t] = colsum[g * IL + t] * (1.0f / PP) + pemean[t];   // m = mean_k hs
  __syncthreads();
  if (t < NC * OL) {
    int c = t >> 4, j = t & 15;
    const float* wr = capsW + (size_t)(c * OL + j) * IL;
    float a = 0;
    for (int i = 0; i < IL; ++i) a += wr[i] * s_l[i];
    v_l[t] = a;                                                        // v0 = mean priors
  }
  __syncthreads();
  const float* hg = h + (size_t)g * PP * IL;

  for (int it = 0; it < NITER; ++it) {
    if (t < NC) {
      float n2 = 0;
#pragma unroll
      for (int j = 0; j < OL; ++j) { float x = v_l[t * OL + j]; n2 += x * x; }
      nrm_l[t] = 1.0f / (sqrtf(n2) + 1e-12f);
    }
    __syncthreads();
    for (int idx = t; idx < NC * IL; idx += 256) {   // u[c][i] = caps_W^T vn
      int c = idx / IL, i = idx - c * IL;
      const float* wr = capsW + (size_t)c * OL * IL + i;
      float a = 0;
#pragma unroll
      for (int j = 0; j < OL; ++j) a += wr[j * IL] * v_l[c * OL + j];
      u_l[idx] = a * nrm_l[c];
    }
    __syncthreads();
    // ---- logits pass: logits[k][c] = (h[ord[k]] + pe[k]) . u_c ----
    float acc[4][NC];
#pragma unroll
    for (int r = 0; r < 4; ++r)
#pragma unroll
      for (int c = 0; c < NC; ++c) acc[r][c] = 0.f;
    const float* hb[4]; const float* pb[4];
#pragma unroll
    for (int r = 0; r < 4; ++r) {
      int k = t + r * 256;
      hb[r] = hg + (size_t)ord[k] * IL;
      pb[r] = pe + (size_t)k * IL;
    }
    for (int i4 = 0; i4 < 24; ++i4) {
      float4 hs4[4];
#pragma unroll
      for (int r = 0; r < 4; ++r) {
        float4 a = *(const float4*)(hb[r] + i4 * 4);
        float4 p = *(const float4*)(pb[r] + i4 * 4);
        hs4[r] = make_float4(a.x + p.x, a.y + p.y, a.z + p.z, a.w + p.w);
      }
#pragma unroll
      for (int c = 0; c < NC; ++c) {
        float4 u4 = *(const float4*)&u_l[c * IL + i4 * 4];
#pragma unroll
        for (int r = 0; r < 4; ++r)
          acc[r][c] += hs4[r].x * u4.x + hs4[r].y * u4.y + hs4[r].z * u4.z + hs4[r].w * u4.w;
      }
    }
    // ---- softmax over k (max, unnormalized exp, sum) ----
    float lmax[NC];
#pragma unroll
    for (int c = 0; c < NC; ++c)
      lmax[c] = fmaxf(fmaxf(acc[0][c], acc[1][c]), fmaxf(acc[2][c], acc[3][c]));
#pragma unroll
    for (int c = 0; c < NC; ++c)
      for (int m = 32; m >= 1; m >>= 1)
        lmax[c] = fmaxf(lmax[c], __shfl_xor(lmax[c], m, 64));
    if (lane == 0)
#pragma unroll
      for (int c = 0; c < NC; ++c) wred[wvi][c] = lmax[c];
    __syncthreads();
    if (t < NC) gmax_l[t] = fmaxf(fmaxf(wred[0][t], wred[1][t]), fmaxf(wred[2][t], wred[3][t]));
    __syncthreads();
    float lsum[NC];
#pragma unroll
    for (int c = 0; c < NC; ++c) lsum[c] = 0.f;
#pragma unroll
    for (int r = 0; r < 4; ++r) {
      int k = t + r * 256;
#pragma unroll
      for (int c = 0; c < NC; ++c) {
        float ev = __expf(acc[r][c] - gmax_l[c]);
        e_l[k * 12 + c] = ev;
        lsum[c] += ev;
      }
    }
#pragma unroll
    for (int c = 0; c < NC; ++c)
      for (int m = 32; m >= 1; m >>= 1)
        lsum[c] += __shfl_xor(lsum[c], m, 64);
    if (lane == 0)
#pragma unroll
      for (int c = 0; c < NC; ++c) wred[wvi][c] = lsum[c];
    __syncthreads();
    if (t < NC) gsum_l[t] = wred[0][t] + wred[1][t] + wred[2][t] + wred[3][t];
    for (int idx = t; idx < NC * IL; idx += 256) s_l[idx] = 0.f;
    __syncthreads();
    // ---- s-pass: s[c][i] = sum_k e[k][c] * hs[k][i]  (32 kstrips x 8 islices) ----
    int isl = t & 7, ks = t >> 3;
    float sl[NC][12];
#pragma unroll
    for (int c = 0; c < NC; ++c)
#pragma unroll
      for (int d = 0; d < 12; ++d) sl[c][d] = 0.f;
    for (int kk = 0; kk < 32; ++kk) {
      int k = ks + 32 * kk;
      int n = ord[k];
      const float* hr = hg + (size_t)n * IL + isl * 12;
      const float* pr = pe + (size_t)k * IL + isl * 12;
      float hv2[12];
#pragma unroll
      for (int q = 0; q < 3; ++q) {
        float4 a = *(const float4*)(hr + q * 4);
        float4 p = *(const float4*)(pr + q * 4);
        hv2[q * 4 + 0] = a.x + p.x; hv2[q * 4 + 1] = a.y + p.y;
        hv2[q * 4 + 2] = a.z + p.z; hv2[q * 4 + 3] = a.w + p.w;
      }
      float4 e0 = *(const float4*)&e_l[k * 12];
      float4 e1 = *(const float4*)&e_l[k * 12 + 4];
      float4 e2 = *(const float4*)&e_l[k * 12 + 8];
      float ev[NC] = {e0.x, e0.y, e0.z, e0.w, e1.x, e1.y, e1.z, e1.w, e2.x, e2.y};
#pragma unroll
      for (int c = 0; c < NC; ++c)
#pragma unroll
        for (int d = 0; d < 12; ++d)
          sl[c][d] += ev[c] * hv2[d];
    }
#pragma unroll
    for (int c = 0; c < NC; ++c)
#pragma unroll
      for (int d = 0; d < 12; ++d) {
        float x = sl[c][d];
        x += __shfl_xor(x, 8, 64);
        x += __shfl_xor(x, 16, 64);
        x += __shfl_xor(x, 32, 64);
        sl[c][d] = x;
      }
    if ((lane >> 3) == 0) {
#pragma unroll
      for (int c = 0; c < NC; ++c)
#pragma unroll
        for (int d = 0; d < 12; ++d)
          atomicAdd(&s_l[c * IL + isl * 12 + d], sl[c][d]);
    }
    __syncthreads();
    // ---- v = caps_W @ s / sumexp ----
    if (t < NC * OL) {
      int c = t >> 4, j = t & 15;
      const float* wr = capsW + (size_t)(c * OL + j) * IL;
      float a = 0;
      for (int i = 0; i < IL; ++i) a += wr[i] * s_l[c * IL + i];
      v_l[t] = a / gsum_l[c];
    }
    __syncthreads();
  }
  if (t < NC) {
    float n2 = 0;
#pragma unroll
    for (int j = 0; j < OL; ++j) { float x = v_l[t * OL + j]; n2 += x * x; }
    out[g * NC + t] = (n2 / (1.0f + n2)) * sqrtf(n2) / sqrtf(n2 + 1e-12f);
  }
}

extern "C" void kernel_launch(void* const* d_in, const int* in_sizes, int n_in,
                              void* d_out, int out_size, void* d_ws, size_t ws_size,
                              hipStream_t stream) {
  const float* x     = (const float*)d_in[0];
  const int*   ei    = (const int*)d_in[1];
  const float* W1    = (const float*)d_in[3];
  const float* b1    = (const float*)d_in[4];
  const float* W2    = (const float*)d_in[5];
  const float* b2    = (const float*)d_in[6];
  const float* W3    = (const float*)d_in[7];
  const float* b3    = (const float*)d_in[8];
  const float* capsW = (const float*)d_in[9];
  float* out = (float*)d_out;

  char* wp = (char*)d_ws;
  auto alloc = [&](size_t bytes) { char* p = wp; wp += (bytes + 255) & ~(size_t)255; return p; };
  float*    degf   = (float*)alloc((size_t)N_NODES * 4);
  float*    dis    = (float*)alloc((size_t)N_NODES * 4);
  float*    h      = (float*)alloc((size_t)N_NODES * IL * 4);
  float*    hlin   = (float*)alloc((size_t)N_NODES * HH * 4);
  unsigned* epack  = (unsigned*)alloc((size_t)NE * 4);
  unsigned* hist   = (unsigned*)alloc((size_t)NCHUNK * NG * 4);
  unsigned* cbase  = (unsigned*)alloc((size_t)NCHUNK * NG * 4);
  unsigned* gbase  = (unsigned*)alloc((size_t)(NG + 1) * 4);
  unsigned* order  = (unsigned*)alloc((size_t)NG * PP * 4);
  float*    colsum = (float*)alloc((size_t)NG * IL * 4);
  float*    pe     = (float*)alloc((size_t)PP * IL * 4);
  float*    pemean = (float*)alloc((size_t)IL * 4);

  hipMemsetAsync(degf, 0, (size_t)N_NODES * 4, stream);
  k_hist<<<NCHUNK, 256, 0, stream>>>(ei, degf, hist);
  k_dis<<<N_NODES / 256, 256, 0, stream>>>(degf, dis);
  k_scan<<<1, 256, 0, stream>>>(hist, cbase, gbase);
  k_scatter<<<NCHUNK, 256, 0, stream>>>(ei, cbase, epack);

  k_gemm<<<N_NODES / 512, 256, 0, stream>>>(x, FIN, FIN, W1, hlin);
  k_agg<<<NG * 4, 256, 0, stream>>>(hlin, dis, epack, gbase, b1, 0, h);
  k_gemm<<<N_NODES / 512, 256, 0, stream>>>(h, IL, HH, W2, hlin);
  k_agg<<<NG * 4, 256, 0, stream>>>(hlin, dis, epack, gbase, b2, 32, h);
  k_gemm<<<N_NODES / 512, 256, 0, stream>>>(h + 32, IL, HH, W3, hlin);
  k_agg<<<NG * 4, 256, 0, stream>>>(hlin, dis, epack, gbase, b3, 64, h);

  k_colsum<<<NG, 256, 0, stream>>>(h, colsum);
  k_sort<<<NG, 256, 0, stream>>>(h, order);
  k_pe<<<(PP * 48) / 256, 256, 0, stream>>>(pe);
  k_pemean<<<1, 128, 0, stream>>>(pe, pemean);
  k_route<<<NG, 256, 0, stream>>>(h, pe, pemean, colsum, order, capsW, out);
}

// Round 3
// 1151.971 us; speedup vs baseline: 2.8502x; 2.7784x over previous
//
#include <hip/hip_runtime.h>
#include <cstdint>
#include <cstddef>

#define N_NODES   262144
#define NG        256
#define PP        1024
#define NE        4194304
#define FIN       128
#define HH        32
#define NC        10
#define OL        16
#define IL        96
#define NITER     3
#define ECHUNK    4096
#define NCHUNK    (NE/ECHUNK)   // 1024
#define ECAP      18432         // per-graph edge capacity (mean 16368, sigma ~128 -> 16 sigma)

// ---------------- per-chunk per-graph edge histogram ----------------
__global__ void k_hist(const int* __restrict__ ei, unsigned* __restrict__ hist) {
  __shared__ unsigned lh[NG];
  int t = threadIdx.x, b = blockIdx.x;
  lh[t] = 0;
  __syncthreads();
  int base = b * ECHUNK;
  for (int q = t; q < ECHUNK; q += 256) {
    int e = base + q;
    int s = ei[e], d = ei[NE + e];
    if (s != d) atomicAdd(&lh[s >> 10], 1u);
  }
  __syncthreads();
  hist[b * NG + t] = lh[t];
}

// ---------------- scan: per-graph bases + per-chunk bases ----------------
__global__ void k_scan(const unsigned* __restrict__ hist, unsigned* __restrict__ cbase,
                       unsigned* __restrict__ gbase) {
  __shared__ unsigned sc[NG];
  int t = threadIdx.x;
  unsigned tot = 0;
  for (int ch = 0; ch < NCHUNK; ++ch) tot += hist[ch * NG + t];
  sc[t] = tot;
  __syncthreads();
  for (int off = 1; off < NG; off <<= 1) {
    unsigned v = (t >= off) ? sc[t - off] : 0u;
    __syncthreads();
    sc[t] += v;
    __syncthreads();
  }
  if (t == 0) gbase[0] = 0;
  gbase[t + 1] = sc[t];                 // inclusive
  unsigned acc = sc[t] - tot;           // exclusive
  for (int ch = 0; ch < NCHUNK; ++ch) {
    cbase[ch * NG + t] = acc;
    acc += hist[ch * NG + t];
  }
}

// ---------------- scatter edges into graph buckets ----------------
__global__ void k_scatter(const int* __restrict__ ei, const unsigned* __restrict__ cbase,
                          unsigned* __restrict__ epack) {
  __shared__ unsigned lcur[NG];
  int t = threadIdx.x, b = blockIdx.x;
  lcur[t] = cbase[b * NG + t];
  __syncthreads();
  int base = b * ECHUNK;
  for (int q = t; q < ECHUNK; q += 256) {
    int e = base + q;
    int s = ei[e], d = ei[NE + e];
    if (s != d) {
      int g = s >> 10;
      unsigned pos = atomicAdd(&lcur[g], 1u);
      epack[pos] = (unsigned)(s & 1023) | ((unsigned)(d & 1023) << 10);
    }
  }
}

// ---------------- per-graph counting sort by dst offset -> CSR + u16 src list ------------
__global__ __launch_bounds__(256) void k_dstsort(const unsigned* __restrict__ epack,
                          const unsigned* __restrict__ gbase,
                          unsigned short* __restrict__ esrc16,
                          unsigned* __restrict__ dstptr) {
  __shared__ unsigned shist[PP];
  __shared__ unsigned wsum[256];
  __shared__ unsigned cur[PP];
  int t = threadIdx.x, g = blockIdx.x;
  unsigned e0 = gbase[g], e1 = gbase[g + 1];
  for (int i = t; i < PP; i += 256) shist[i] = 0;
  __syncthreads();
  for (unsigned e = e0 + t; e < e1; e += 256)
    atomicAdd(&shist[(epack[e] >> 10) & 1023], 1u);
  __syncthreads();
  unsigned h0 = shist[4 * t], h1 = shist[4 * t + 1], h2 = shist[4 * t + 2], h3 = shist[4 * t + 3];
  unsigned tsum = h0 + h1 + h2 + h3;
  wsum[t] = tsum;
  __syncthreads();
  for (int off = 1; off < 256; off <<= 1) {
    unsigned v = (t >= off) ? wsum[t - off] : 0u;
    __syncthreads();
    wsum[t] += v;
    __syncthreads();
  }
  unsigned excl = wsum[t] - tsum;       // local 0-based positions
  unsigned c0 = excl, c1 = c0 + h0, c2 = c1 + h1, c3 = c2 + h2;
  cur[4 * t] = c0; cur[4 * t + 1] = c1; cur[4 * t + 2] = c2; cur[4 * t + 3] = c3;
  unsigned* dp = dstptr + (size_t)g * (PP + 1);
  dp[4 * t] = c0; dp[4 * t + 1] = c1; dp[4 * t + 2] = c2; dp[4 * t + 3] = c3;
  if (t == 0) dp[PP] = e1 - e0;
  __syncthreads();
  unsigned short* eg = esrc16 + (size_t)g * ECAP;
  for (unsigned e = e0 + t; e < e1; e += 256) {
    unsigned pk = epack[e];
    unsigned so = pk & 1023, dofs = (pk >> 10) & 1023;
    unsigned pos = atomicAdd(&cur[dofs], 1u);
    if (pos < ECAP) eg[pos] = (unsigned short)so;
  }
}

// ---------------- dis from CSR degrees ----------------
__global__ void k_dis(const unsigned* __restrict__ dstptr, float* __restrict__ dis) {
  int n = blockIdx.x * 256 + threadIdx.x;
  int g = n >> 10, k = n & 1023;
  const unsigned* dp = dstptr + (size_t)g * (PP + 1) + k;
  float deg = (float)(dp[1] - dp[0]);
  dis[n] = 1.0f / sqrtf(deg + 1.0f);
}

// ---------------- fp32 GEMM: out(N x 32) = xin(N x K, row stride ldx) @ W(K x 32) ----------------
__global__ __launch_bounds__(256) void k_gemm(const float* __restrict__ xin, int ldx, int K,
                                              const float* __restrict__ W,
                                              float* __restrict__ out) {
  __shared__ float Wt[32 * (FIN + 4)];
  int t = threadIdx.x, b = blockIdx.x;
  int stride = K + 4;
  for (int idx = t; idx < K * 32; idx += 256) {
    int k = idx >> 5, c = idx & 31;
    Wt[c * stride + k] = W[idx];
  }
  __syncthreads();
  int cg = t & 3, ng = t >> 2;
  int row0 = b * 512 + ng * 8;
  float acc[8][8];
#pragma unroll
  for (int r = 0; r < 8; ++r)
#pragma unroll
    for (int j = 0; j < 8; ++j) acc[r][j] = 0.f;
  for (int k4 = 0; k4 < (K >> 2); ++k4) {
    float4 xv[8];
#pragma unroll
    for (int r = 0; r < 8; ++r)
      xv[r] = *(const float4*)(xin + (size_t)(row0 + r) * ldx + k4 * 4);
    float4 wvv[8];
#pragma unroll
    for (int j = 0; j < 8; ++j)
      wvv[j] = *(const float4*)&Wt[(cg + 4 * j) * stride + k4 * 4];
#pragma unroll
    for (int j = 0; j < 8; ++j)
#pragma unroll
      for (int r = 0; r < 8; ++r)
        acc[r][j] += xv[r].x * wvv[j].x + xv[r].y * wvv[j].y + xv[r].z * wvv[j].z + xv[r].w * wvv[j].w;
  }
#pragma unroll
  for (int r = 0; r < 8; ++r)
#pragma unroll
    for (int j = 0; j < 8; ++j)
      out[(size_t)(row0 + r) * HH + cg + 4 * j] = acc[r][j];
}

// ---------------- aggregation: dst-owned register accumulation, no atomics ----------------
// agg_ref[n] = dis[n] * sum_{e:dst=n} dis[src]*hlin[src] + dis[n]^2*hlin[n]
// hs[k][c] = hlin[k][c]*dis[k] (row-major, 8 ch/block); acc over CSR segment; epilogue tanh.
__global__ __launch_bounds__(256) void k_agg(const float* __restrict__ hlin,
                                             const float* __restrict__ dis,
                                             const unsigned short* __restrict__ esrc16,
                                             const unsigned* __restrict__ dstptr,
                                             const float* __restrict__ bias,
                                             int coloff,
                                             float* __restrict__ h) {
  __shared__ float hsl[PP * 8];          // 32 KiB, [k][c]
  __shared__ uint4 elv4[ECAP / 8];       // 36 KiB, u16 src offsets
  const unsigned short* el = (const unsigned short*)elv4;
  int t = threadIdx.x;
  int g = blockIdx.x >> 2, q = blockIdx.x & 3;
  int c0 = q * 8;
  const unsigned* dp = dstptr + (size_t)g * (PP + 1);
  unsigned cnt = dp[PP];
  float dv[4];
  unsigned p0[4], p1[4];
#pragma unroll
  for (int r = 0; r < 4; ++r) {
    int k = t + r * 256;
    float d = dis[g * PP + k];
    dv[r] = d;
    const float* row = hlin + (size_t)(g * PP + k) * HH + c0;
    float4 a = *(const float4*)row;
    float4 b2 = *(const float4*)(row + 4);
    float* o = &hsl[k * 8];
    o[0] = a.x * d; o[1] = a.y * d; o[2] = a.z * d; o[3] = a.w * d;
    o[4] = b2.x * d; o[5] = b2.y * d; o[6] = b2.z * d; o[7] = b2.w * d;
    p0[r] = dp[k]; p1[r] = dp[k + 1];
  }
  const uint4* egv = (const uint4*)(esrc16 + (size_t)g * ECAP);
  int nv = (int)((cnt + 7) >> 3);
  for (int i = t; i < nv; i += 256) elv4[i] = egv[i];
  __syncthreads();
  float bl[8];
#pragma unroll
  for (int c = 0; c < 8; ++c) bl[c] = bias[c0 + c];
#pragma unroll
  for (int r = 0; r < 4; ++r) {
    int k = t + r * 256;
    float acc[8];
    const float* selfp = &hsl[k * 8];
#pragma unroll
    for (int c = 0; c < 8; ++c) acc[c] = selfp[c];     // self-loop term
    unsigned e = p0[r], eend = p1[r];
    for (; e + 1 < eend; e += 2) {                     // 2-edge unroll for ILP
      unsigned so0 = el[e], so1 = el[e + 1];
      const float* s0 = &hsl[so0 * 8];
      const float* s1 = &hsl[so1 * 8];
      float4 a0 = *(const float4*)s0;
      float4 b0 = *(const float4*)(s0 + 4);
      float4 a1 = *(const float4*)s1;
      float4 b1 = *(const float4*)(s1 + 4);
      acc[0] += a0.x + a1.x; acc[1] += a0.y + a1.y;
      acc[2] += a0.z + a1.z; acc[3] += a0.w + a1.w;
      acc[4] += b0.x + b1.x; acc[5] += b0.y + b1.y;
      acc[6] += b0.z + b1.z; acc[7] += b0.w + b1.w;
    }
    if (e < eend) {
      unsigned so0 = el[e];
      const float* s0 = &hsl[so0 * 8];
      float4 a0 = *(const float4*)s0;
      float4 b0 = *(const float4*)(s0 + 4);
      acc[0] += a0.x; acc[1] += a0.y; acc[2] += a0.z; acc[3] += a0.w;
      acc[4] += b0.x; acc[5] += b0.y; acc[6] += b0.z; acc[7] += b0.w;
    }
    float* orow = h + (size_t)(g * PP + k) * IL + coloff + c0;
#pragma unroll
    for (int c = 0; c < 8; ++c)
      orow[c] = tanhf(dv[r] * acc[c] + bl[c]);
  }
}

// ---------------- per-graph column sums of h ----------------
__global__ void k_colsum(const float* __restrict__ h, float* __restrict__ colsum) {
  __shared__ float cs[IL];
  int t = threadIdx.x, g = blockIdx.x;
  if (t < IL) cs[t] = 0.f;
  __syncthreads();
  for (int idx = t; idx < PP * 24; idx += 256) {
    int k = idx / 24, i4 = idx % 24;
    float4 v = *(const float4*)(h + (size_t)(g * PP + k) * IL + i4 * 4);
    atomicAdd(&cs[i4 * 4 + 0], v.x);
    atomicAdd(&cs[i4 * 4 + 1], v.y);
    atomicAdd(&cs[i4 * 4 + 2], v.z);
    atomicAdd(&cs[i4 * 4 + 3], v.w);
  }
  __syncthreads();
  if (t < IL) colsum[g * IL + t] = cs[t];
}

// ---------------- per-graph stable descending sort by last channel (bitonic) ----------------
__global__ void k_sort(const float* __restrict__ h, unsigned* __restrict__ order) {
  __shared__ float key[PP];
  __shared__ unsigned sidx[PP];
  int t = threadIdx.x, g = blockIdx.x;
  for (int i = t; i < PP; i += 256) {
    key[i] = h[(size_t)(g * PP + i) * IL + (IL - 1)];
    sidx[i] = i;
  }
  __syncthreads();
  for (int sz = 2; sz <= PP; sz <<= 1) {
    for (int st = sz >> 1; st > 0; st >>= 1) {
      for (int q = t; q < PP / 2; q += 256) {
        int i = 2 * q - (q & (st - 1));
        int j = i + st;
        float ki = key[i], kj = key[j];
        unsigned ii = sidx[i], ij = sidx[j];
        bool less_ji = (kj > ki) || (kj == ki && ij < ii);
        bool asc = ((i & sz) == 0);
        if (less_ji == asc) { key[i] = kj; key[j] = ki; sidx[i] = ij; sidx[j] = ii; }
      }
      __syncthreads();
    }
  }
  for (int i = t; i < PP; i += 256) order[g * PP + i] = sidx[i];
}

// ---------------- position encoding ----------------
__global__ void k_pe(float* __restrict__ pe) {
  int id = blockIdx.x * 256 + threadIdx.x;
  if (id >= PP * 48) return;
  int pos = id / 48, i = id % 48;
  float denom = powf(10000.0f, (2.0f * i) / 96.0f);
  float ang = (float)pos / denom;
  pe[pos * IL + 2 * i] = sinf(ang);
  pe[pos * IL + 2 * i + 1] = cosf(ang);
}

__global__ void k_pemean(const float* __restrict__ pe, float* __restrict__ pemean) {
  int t = threadIdx.x;
  if (t >= IL) return;
  float s = 0;
  for (int p = 0; p < PP; ++p) s += pe[p * IL + t];
  pemean[t] = s * (1.0f / PP);
}

// ---------------- capsule k-means routing, one block per graph ----------------
__global__ __launch_bounds__(256) void k_route(const float* __restrict__ h,
                                               const float* __restrict__ pe,
                                               const float* __restrict__ pemean,
                                               const float* __restrict__ colsum,
                                               const unsigned* __restrict__ order,
                                               const float* __restrict__ capsW,
                                               float* __restrict__ out) {
  __shared__ unsigned ord[PP];
  __shared__ float u_l[NC * IL];
  __shared__ float e_l[PP * 12];
  __shared__ float s_l[NC * IL];
  __shared__ float v_l[NC * OL];
  __shared__ float nrm_l[NC];
  __shared__ float gmax_l[NC], gsum_l[NC];
  __shared__ float wred[4][NC];
  int t = threadIdx.x, g = blockIdx.x;
  int lane = t & 63, wvi = t >> 6;
  for (int i = t; i < PP; i += 256) ord[i] = order[g * PP + i];
  if (t < IL) s_l[t] = colsum[g * IL + t] * (1.0f / PP) + pemean[t];   // m = mean_k hs
  __syncthreads();
  if (t < NC * OL) {
    int c = t >> 4, j = t & 15;
    const float* wr = capsW + (size_t)(c * OL + j) * IL;
    float a = 0;
    for (int i = 0; i < IL; ++i) a += wr[i] * s_l[i];
    v_l[t] = a;                                                        // v0 = mean priors
  }
  __syncthreads();
  const float* hg = h + (size_t)g * PP * IL;

  for (int it = 0; it < NITER; ++it) {
    if (t < NC) {
      float n2 = 0;
#pragma unroll
      for (int j = 0; j < OL; ++j) { float x = v_l[t * OL + j]; n2 += x * x; }
      nrm_l[t] = 1.0f / (sqrtf(n2) + 1e-12f);
    }
    __syncthreads();
    for (int idx = t; idx < NC * IL; idx += 256) {   // u[c][i] = caps_W^T vn
      int c = idx / IL, i = idx - c * IL;
      const float* wr = capsW + (size_t)c * OL * IL + i;
      float a = 0;
#pragma unroll
      for (int j = 0; j < OL; ++j) a += wr[j * IL] * v_l[c * OL + j];
      u_l[idx] = a * nrm_l[c];
    }
    __syncthreads();
    // ---- logits pass: logits[k][c] = (h[ord[k]] + pe[k]) . u_c ----
    float acc[4][NC];
#pragma unroll
    for (int r = 0; r < 4; ++r)
#pragma unroll
      for (int c = 0; c < NC; ++c) acc[r][c] = 0.f;
    const float* hb[4]; const float* pb[4];
#pragma unroll
    for (int r = 0; r < 4; ++r) {
      int k = t + r * 256;
      hb[r] = hg + (size_t)ord[k] * IL;
      pb[r] = pe + (size_t)k * IL;
    }
    for (int i4 = 0; i4 < 24; ++i4) {
      float4 hs4[4];
#pragma unroll
      for (int r = 0; r < 4; ++r) {
        float4 a = *(const float4*)(hb[r] + i4 * 4);
        float4 p = *(const float4*)(pb[r] + i4 * 4);
        hs4[r] = make_float4(a.x + p.x, a.y + p.y, a.z + p.z, a.w + p.w);
      }
#pragma unroll
      for (int c = 0; c < NC; ++c) {
        float4 u4 = *(const float4*)&u_l[c * IL + i4 * 4];
#pragma unroll
        for (int r = 0; r < 4; ++r)
          acc[r][c] += hs4[r].x * u4.x + hs4[r].y * u4.y + hs4[r].z * u4.z + hs4[r].w * u4.w;
      }
    }
    // ---- softmax over k (max, unnormalized exp, sum) ----
    float lmax[NC];
#pragma unroll
    for (int c = 0; c < NC; ++c)
      lmax[c] = fmaxf(fmaxf(acc[0][c], acc[1][c]), fmaxf(acc[2][c], acc[3][c]));
#pragma unroll
    for (int c = 0; c < NC; ++c)
      for (int m = 32; m >= 1; m >>= 1)
        lmax[c] = fmaxf(lmax[c], __shfl_xor(lmax[c], m, 64));
    if (lane == 0)
#pragma unroll
      for (int c = 0; c < NC; ++c) wred[wvi][c] = lmax[c];
    __syncthreads();
    if (t < NC) gmax_l[t] = fmaxf(fmaxf(wred[0][t], wred[1][t]), fmaxf(wred[2][t], wred[3][t]));
    __syncthreads();
    float lsum[NC];
#pragma unroll
    for (int c = 0; c < NC; ++c) lsum[c] = 0.f;
#pragma unroll
    for (int r = 0; r < 4; ++r) {
      int k = t + r * 256;
#pragma unroll
      for (int c = 0; c < NC; ++c) {
        float ev = __expf(acc[r][c] - gmax_l[c]);
        e_l[k * 12 + c] = ev;
        lsum[c] += ev;
      }
    }
#pragma unroll
    for (int c = 0; c < NC; ++c)
      for (int m = 32; m >= 1; m >>= 1)
        lsum[c] += __shfl_xor(lsum[c], m, 64);
    if (lane == 0)
#pragma unroll
      for (int c = 0; c < NC; ++c) wred[wvi][c] = lsum[c];
    __syncthreads();
    if (t < NC) gsum_l[t] = wred[0][t] + wred[1][t] + wred[2][t] + wred[3][t];
    for (int idx = t; idx < NC * IL; idx += 256) s_l[idx] = 0.f;
    __syncthreads();
    // ---- s-pass: s[c][i] = sum_k e[k][c] * hs[k][i]  (32 kstrips x 8 islices) ----
    int isl = t & 7, ks = t >> 3;
    float sl[NC][12];
#pragma unroll
    for (int c = 0; c < NC; ++c)
#pragma unroll
      for (int d = 0; d < 12; ++d) sl[c][d] = 0.f;
    for (int kk = 0; kk < 32; ++kk) {
      int k = ks + 32 * kk;
      int n = ord[k];
      const float* hr = hg + (size_t)n * IL + isl * 12;
      const float* pr = pe + (size_t)k * IL + isl * 12;
      float hv2[12];
#pragma unroll
      for (int q = 0; q < 3; ++q) {
        float4 a = *(const float4*)(hr + q * 4);
        float4 p = *(const float4*)(pr + q * 4);
        hv2[q * 4 + 0] = a.x + p.x; hv2[q * 4 + 1] = a.y + p.y;
        hv2[q * 4 + 2] = a.z + p.z; hv2[q * 4 + 3] = a.w + p.w;
      }
      float4 e0 = *(const float4*)&e_l[k * 12];
      float4 e1 = *(const float4*)&e_l[k * 12 + 4];
      float4 e2 = *(const float4*)&e_l[k * 12 + 8];
      float ev[NC] = {e0.x, e0.y, e0.z, e0.w, e1.x, e1.y, e1.z, e1.w, e2.x, e2.y};
#pragma unroll
      for (int c = 0; c < NC; ++c)
#pragma unroll
        for (int d = 0; d < 12; ++d)
          sl[c][d] += ev[c] * hv2[d];
    }
#pragma unroll
    for (int c = 0; c < NC; ++c)
#pragma unroll
      for (int d = 0; d < 12; ++d) {
        float x = sl[c][d];
        x += __shfl_xor(x, 8, 64);
        x += __shfl_xor(x, 16, 64);
        x += __shfl_xor(x, 32, 64);
        sl[c][d] = x;
      }
    if ((lane >> 3) == 0) {
#pragma unroll
      for (int c = 0; c < NC; ++c)
#pragma unroll
        for (int d = 0; d < 12; ++d)
          atomicAdd(&s_l[c * IL + isl * 12 + d], sl[c][d]);
    }
    __syncthreads();
    // ---- v = caps_W @ s / sumexp ----
    if (t < NC * OL) {
      int c = t >> 4, j = t & 15;
      const float* wr = capsW + (size_t)(c * OL + j) * IL;
      float a = 0;
      for (int i = 0; i < IL; ++i) a += wr[i] * s_l[c * IL + i];
      v_l[t] = a / gsum_l[c];
    }
    __syncthreads();
  }
  if (t < NC) {
    float n2 = 0;
#pragma unroll
    for (int j = 0; j < OL; ++j) { float x = v_l[t * OL + j]; n2 += x * x; }
    out[g * NC + t] = (n2 / (1.0f + n2)) * sqrtf(n2) / sqrtf(n2 + 1e-12f);
  }
}

extern "C" void kernel_launch(void* const* d_in, const int* in_sizes, int n_in,
                              void* d_out, int out_size, void* d_ws, size_t ws_size,
                              hipStream_t stream) {
  const float* x     = (const float*)d_in[0];
  const int*   ei    = (const int*)d_in[1];
  const float* W1    = (const float*)d_in[3];
  const float* b1    = (const float*)d_in[4];
  const float* W2    = (const float*)d_in[5];
  const float* b2    = (const float*)d_in[6];
  const float* W3    = (const float*)d_in[7];
  const float* b3    = (const float*)d_in[8];
  const float* capsW = (const float*)d_in[9];
  float* out = (float*)d_out;

  char* wp = (char*)d_ws;
  auto alloc = [&](size_t bytes) { char* p = wp; wp += (bytes + 255) & ~(size_t)255; return p; };
  float*    dis    = (float*)alloc((size_t)N_NODES * 4);
  float*    h      = (float*)alloc((size_t)N_NODES * IL * 4);
  float*    hlin   = (float*)alloc((size_t)N_NODES * HH * 4);
  unsigned* epack  = (unsigned*)alloc((size_t)NE * 4);
  unsigned short* esrc16 = (unsigned short*)alloc((size_t)NG * ECAP * 2);
  unsigned* dstptr = (unsigned*)alloc((size_t)NG * (PP + 1) * 4);
  unsigned* hist   = (unsigned*)alloc((size_t)NCHUNK * NG * 4);
  unsigned* cbase  = (unsigned*)alloc((size_t)NCHUNK * NG * 4);
  unsigned* gbase  = (unsigned*)alloc((size_t)(NG + 1) * 4);
  unsigned* order  = (unsigned*)alloc((size_t)NG * PP * 4);
  float*    colsum = (float*)alloc((size_t)NG * IL * 4);
  float*    pe     = (float*)alloc((size_t)PP * IL * 4);
  float*    pemean = (float*)alloc((size_t)IL * 4);

  k_hist<<<NCHUNK, 256, 0, stream>>>(ei, hist);
  k_scan<<<1, 256, 0, stream>>>(hist, cbase, gbase);
  k_scatter<<<NCHUNK, 256, 0, stream>>>(ei, cbase, epack);
  k_dstsort<<<NG, 256, 0, stream>>>(epack, gbase, esrc16, dstptr);
  k_dis<<<N_NODES / 256, 256, 0, stream>>>(dstptr, dis);

  k_gemm<<<N_NODES / 512, 256, 0, stream>>>(x, FIN, FIN, W1, hlin);
  k_agg<<<NG * 4, 256, 0, stream>>>(hlin, dis, esrc16, dstptr, b1, 0, h);
  k_gemm<<<N_NODES / 512, 256, 0, stream>>>(h, IL, HH, W2, hlin);
  k_agg<<<NG * 4, 256, 0, stream>>>(hlin, dis, esrc16, dstptr, b2, 32, h);
  k_gemm<<<N_NODES / 512, 256, 0, stream>>>(h + 32, IL, HH, W3, hlin);
  k_agg<<<NG * 4, 256, 0, stream>>>(hlin, dis, esrc16, dstptr, b3, 64, h);

  k_colsum<<<NG, 256, 0, stream>>>(h, colsum);
  k_sort<<<NG, 256, 0, stream>>>(h, order);
  k_pe<<<(PP * 48) / 256, 256, 0, stream>>>(pe);
  k_pemean<<<1, 128, 0, stream>>>(pe, pemean);
  k_route<<<NG, 256, 0, stream>>>(h, pe, pemean, colsum, order, capsW, out);
}

// Round 4
// 956.059 us; speedup vs baseline: 3.4342x; 1.2049x over previous
//
#include <hip/hip_runtime.h>
#include <hip/hip_fp16.h>
#include <cstdint>
#include <cstddef>

#define N_NODES   262144
#define NG        256
#define PP        1024
#define NE        4194304
#define FIN       128
#define HH        32
#define NC        10
#define OL        16
#define IL        96
#define NITER     3
#define ECHUNK    4096
#define NCHUNK    (NE/ECHUNK)   // 1024
#define ECAP      18432         // per-graph edge capacity (mean 16368, sigma ~128 -> 16 sigma)

// ---------------- per-chunk per-graph edge histogram ----------------
__global__ void k_hist(const int* __restrict__ ei, unsigned* __restrict__ hist) {
  __shared__ unsigned lh[NG];
  int t = threadIdx.x, b = blockIdx.x;
  lh[t] = 0;
  __syncthreads();
  int base = b * ECHUNK;
  for (int q = t; q < ECHUNK; q += 256) {
    int e = base + q;
    int s = ei[e], d = ei[NE + e];
    if (s != d) atomicAdd(&lh[s >> 10], 1u);
  }
  __syncthreads();
  hist[b * NG + t] = lh[t];
}

// ---------------- scan: per-graph bases + per-chunk bases ----------------
__global__ void k_scan(const unsigned* __restrict__ hist, unsigned* __restrict__ cbase,
                       unsigned* __restrict__ gbase) {
  __shared__ unsigned sc[NG];
  int t = threadIdx.x;
  unsigned tot = 0;
  for (int ch = 0; ch < NCHUNK; ++ch) tot += hist[ch * NG + t];
  sc[t] = tot;
  __syncthreads();
  for (int off = 1; off < NG; off <<= 1) {
    unsigned v = (t >= off) ? sc[t - off] : 0u;
    __syncthreads();
    sc[t] += v;
    __syncthreads();
  }
  if (t == 0) gbase[0] = 0;
  gbase[t + 1] = sc[t];                 // inclusive
  unsigned acc = sc[t] - tot;           // exclusive
  for (int ch = 0; ch < NCHUNK; ++ch) {
    cbase[ch * NG + t] = acc;
    acc += hist[ch * NG + t];
  }
}

// ---------------- scatter edges into graph buckets ----------------
__global__ void k_scatter(const int* __restrict__ ei, const unsigned* __restrict__ cbase,
                          unsigned* __restrict__ epack) {
  __shared__ unsigned lcur[NG];
  int t = threadIdx.x, b = blockIdx.x;
  lcur[t] = cbase[b * NG + t];
  __syncthreads();
  int base = b * ECHUNK;
  for (int q = t; q < ECHUNK; q += 256) {
    int e = base + q;
    int s = ei[e], d = ei[NE + e];
    if (s != d) {
      int g = s >> 10;
      unsigned pos = atomicAdd(&lcur[g], 1u);
      epack[pos] = (unsigned)(s & 1023) | ((unsigned)(d & 1023) << 10);
    }
  }
}

// ---------------- per-graph counting sort by dst offset -> CSR + u16 src list ------------
__global__ __launch_bounds__(256) void k_dstsort(const unsigned* __restrict__ epack,
                          const unsigned* __restrict__ gbase,
                          unsigned short* __restrict__ esrc16,
                          unsigned* __restrict__ dstptr) {
  __shared__ unsigned shist[PP];
  __shared__ unsigned wsum[256];
  __shared__ unsigned cur[PP];
  int t = threadIdx.x, g = blockIdx.x;
  unsigned e0 = gbase[g], e1 = gbase[g + 1];
  for (int i = t; i < PP; i += 256) shist[i] = 0;
  __syncthreads();
  for (unsigned e = e0 + t; e < e1; e += 256)
    atomicAdd(&shist[(epack[e] >> 10) & 1023], 1u);
  __syncthreads();
  unsigned h0 = shist[4 * t], h1 = shist[4 * t + 1], h2 = shist[4 * t + 2], h3 = shist[4 * t + 3];
  unsigned tsum = h0 + h1 + h2 + h3;
  wsum[t] = tsum;
  __syncthreads();
  for (int off = 1; off < 256; off <<= 1) {
    unsigned v = (t >= off) ? wsum[t - off] : 0u;
    __syncthreads();
    wsum[t] += v;
    __syncthreads();
  }
  unsigned excl = wsum[t] - tsum;       // local 0-based positions
  unsigned c0 = excl, c1 = c0 + h0, c2 = c1 + h1, c3 = c2 + h2;
  cur[4 * t] = c0; cur[4 * t + 1] = c1; cur[4 * t + 2] = c2; cur[4 * t + 3] = c3;
  unsigned* dp = dstptr + (size_t)g * (PP + 1);
  dp[4 * t] = c0; dp[4 * t + 1] = c1; dp[4 * t + 2] = c2; dp[4 * t + 3] = c3;
  if (t == 0) dp[PP] = e1 - e0;
  __syncthreads();
  unsigned short* eg = esrc16 + (size_t)g * ECAP;
  for (unsigned e = e0 + t; e < e1; e += 256) {
    unsigned pk = epack[e];
    unsigned so = pk & 1023, dofs = (pk >> 10) & 1023;
    unsigned pos = atomicAdd(&cur[dofs], 1u);
    if (pos < ECAP) eg[pos] = (unsigned short)so;
  }
}

// ---------------- dis from CSR degrees ----------------
__global__ void k_dis(const unsigned* __restrict__ dstptr, float* __restrict__ dis) {
  int n = blockIdx.x * 256 + threadIdx.x;
  int g = n >> 10, k = n & 1023;
  const unsigned* dp = dstptr + (size_t)g * (PP + 1) + k;
  float deg = (float)(dp[1] - dp[0]);
  dis[n] = 1.0f / sqrtf(deg + 1.0f);
}

// ---------------- fp32 GEMM: out(N x 32) = xin(N x K, row stride ldx) @ W(K x 32) ----------------
__global__ __launch_bounds__(256) void k_gemm(const float* __restrict__ xin, int ldx, int K,
                                              const float* __restrict__ W,
                                              float* __restrict__ out) {
  __shared__ float Wt[32 * (FIN + 4)];
  int t = threadIdx.x, b = blockIdx.x;
  int stride = K + 4;
  for (int idx = t; idx < K * 32; idx += 256) {
    int k = idx >> 5, c = idx & 31;
    Wt[c * stride + k] = W[idx];
  }
  __syncthreads();
  int cg = t & 3, ng = t >> 2;
  int row0 = b * 512 + ng * 8;
  float acc[8][8];
#pragma unroll
  for (int r = 0; r < 8; ++r)
#pragma unroll
    for (int j = 0; j < 8; ++j) acc[r][j] = 0.f;
  for (int k4 = 0; k4 < (K >> 2); ++k4) {
    float4 xv[8];
#pragma unroll
    for (int r = 0; r < 8; ++r)
      xv[r] = *(const float4*)(xin + (size_t)(row0 + r) * ldx + k4 * 4);
    float4 wvv[8];
#pragma unroll
    for (int j = 0; j < 8; ++j)
      wvv[j] = *(const float4*)&Wt[(cg + 4 * j) * stride + k4 * 4];
#pragma unroll
    for (int j = 0; j < 8; ++j)
#pragma unroll
      for (int r = 0; r < 8; ++r)
        acc[r][j] += xv[r].x * wvv[j].x + xv[r].y * wvv[j].y + xv[r].z * wvv[j].z + xv[r].w * wvv[j].w;
  }
#pragma unroll
  for (int r = 0; r < 8; ++r)
#pragma unroll
    for (int j = 0; j < 8; ++j)
      out[(size_t)(row0 + r) * HH + cg + 4 * j] = acc[r][j];
}

// ---------------- aggregation: dst-owned register accumulation, no atomics -----------
// Also folds per-graph column sums of tanh output into global colsum via wave reduction.
__global__ __launch_bounds__(256) void k_agg(const float* __restrict__ hlin,
                                             const float* __restrict__ dis,
                                             const unsigned short* __restrict__ esrc16,
                                             const unsigned* __restrict__ dstptr,
                                             const float* __restrict__ bias,
                                             int coloff,
                                             float* __restrict__ h,
                                             float* __restrict__ colsum) {
  __shared__ float hsl[PP * 8];          // 32 KiB, [k][c]
  __shared__ uint4 elv4[ECAP / 8];       // 36 KiB, u16 src offsets
  const unsigned short* el = (const unsigned short*)elv4;
  int t = threadIdx.x;
  int g = blockIdx.x >> 2, q = blockIdx.x & 3;
  int c0 = q * 8;
  int lane = t & 63;
  const unsigned* dp = dstptr + (size_t)g * (PP + 1);
  unsigned cnt = dp[PP];
  float dv[4];
  unsigned p0[4], p1[4];
#pragma unroll
  for (int r = 0; r < 4; ++r) {
    int k = t + r * 256;
    float d = dis[g * PP + k];
    dv[r] = d;
    const float* row = hlin + (size_t)(g * PP + k) * HH + c0;
    float4 a = *(const float4*)row;
    float4 b2 = *(const float4*)(row + 4);
    float* o = &hsl[k * 8];
    o[0] = a.x * d; o[1] = a.y * d; o[2] = a.z * d; o[3] = a.w * d;
    o[4] = b2.x * d; o[5] = b2.y * d; o[6] = b2.z * d; o[7] = b2.w * d;
    p0[r] = dp[k]; p1[r] = dp[k + 1];
  }
  const uint4* egv = (const uint4*)(esrc16 + (size_t)g * ECAP);
  int nv = (int)((cnt + 7) >> 3);
  for (int i = t; i < nv; i += 256) elv4[i] = egv[i];
  __syncthreads();
  float bl[8];
#pragma unroll
  for (int c = 0; c < 8; ++c) bl[c] = bias[c0 + c];
  float csum[8];
#pragma unroll
  for (int c = 0; c < 8; ++c) csum[c] = 0.f;
#pragma unroll
  for (int r = 0; r < 4; ++r) {
    int k = t + r * 256;
    float acc[8];
    const float* selfp = &hsl[k * 8];
#pragma unroll
    for (int c = 0; c < 8; ++c) acc[c] = selfp[c];     // self-loop term
    unsigned e = p0[r], eend = p1[r];
    for (; e + 1 < eend; e += 2) {                     // 2-edge unroll for ILP
      unsigned so0 = el[e], so1 = el[e + 1];
      const float* s0 = &hsl[so0 * 8];
      const float* s1 = &hsl[so1 * 8];
      float4 a0 = *(const float4*)s0;
      float4 b0 = *(const float4*)(s0 + 4);
      float4 a1 = *(const float4*)s1;
      float4 b1 = *(const float4*)(s1 + 4);
      acc[0] += a0.x + a1.x; acc[1] += a0.y + a1.y;
      acc[2] += a0.z + a1.z; acc[3] += a0.w + a1.w;
      acc[4] += b0.x + b1.x; acc[5] += b0.y + b1.y;
      acc[6] += b0.z + b1.z; acc[7] += b0.w + b1.w;
    }
    if (e < eend) {
      unsigned so0 = el[e];
      const float* s0 = &hsl[so0 * 8];
      float4 a0 = *(const float4*)s0;
      float4 b0 = *(const float4*)(s0 + 4);
      acc[0] += a0.x; acc[1] += a0.y; acc[2] += a0.z; acc[3] += a0.w;
      acc[4] += b0.x; acc[5] += b0.y; acc[6] += b0.z; acc[7] += b0.w;
    }
    float* orow = h + (size_t)(g * PP + k) * IL + coloff + c0;
#pragma unroll
    for (int c = 0; c < 8; ++c) {
      float o = tanhf(dv[r] * acc[c] + bl[c]);
      orow[c] = o;
      csum[c] += o;
    }
  }
  // wave-reduce column sums, one global atomic per (wave, channel)
#pragma unroll
  for (int m = 1; m <= 32; m <<= 1)
#pragma unroll
    for (int c = 0; c < 8; ++c) csum[c] += __shfl_xor(csum[c], m, 64);
  if (lane == 0) {
#pragma unroll
    for (int c = 0; c < 8; ++c)
      atomicAdd(&colsum[g * IL + coloff + c0 + c], csum[c]);
  }
}

// ---------------- per-graph stable descending sort by last channel (bitonic) ----------------
// writes rank16: rank[original_node] = sorted_position
__global__ void k_sort(const float* __restrict__ h, unsigned short* __restrict__ rank16) {
  __shared__ float key[PP];
  __shared__ unsigned sidx[PP];
  int t = threadIdx.x, g = blockIdx.x;
  for (int i = t; i < PP; i += 256) {
    key[i] = h[(size_t)(g * PP + i) * IL + (IL - 1)];
    sidx[i] = i;
  }
  __syncthreads();
  for (int sz = 2; sz <= PP; sz <<= 1) {
    for (int st = sz >> 1; st > 0; st >>= 1) {
      for (int q = t; q < PP / 2; q += 256) {
        int i = 2 * q - (q & (st - 1));
        int j = i + st;
        float ki = key[i], kj = key[j];
        unsigned ii = sidx[i], ij = sidx[j];
        bool less_ji = (kj > ki) || (kj == ki && ij < ii);
        bool asc = ((i & sz) == 0);
        if (less_ji == asc) { key[i] = kj; key[j] = ki; sidx[i] = ij; sidx[j] = ii; }
      }
      __syncthreads();
    }
  }
  for (int i = t; i < PP; i += 256) rank16[g * PP + sidx[i]] = (unsigned short)i;
}

// ---------------- position encoding ----------------
__global__ void k_pe(float* __restrict__ pe) {
  int id = blockIdx.x * 256 + threadIdx.x;
  if (id >= PP * 48) return;
  int pos = id / 48, i = id % 48;
  float denom = powf(10000.0f, (2.0f * i) / 96.0f);
  float ang = (float)pos / denom;
  pe[pos * IL + 2 * i] = sinf(ang);
  pe[pos * IL + 2 * i + 1] = cosf(ang);
}

__global__ void k_pemean(const float* __restrict__ pe, float* __restrict__ pemean) {
  int t = threadIdx.x;
  if (t >= IL) return;
  float s = 0;
  for (int p = 0; p < PP; ++p) s += pe[p * IL + t];
  pemean[t] = s * (1.0f / PP);
}

// ---------------- build hs = h + pe[rank[n]] as fp16, contiguous ----------------
__global__ __launch_bounds__(256) void k_mkhs(const float* __restrict__ h,
                                              const float* __restrict__ pe,
                                              const unsigned short* __restrict__ rank16,
                                              __half* __restrict__ hs) {
  int t = threadIdx.x, g = blockIdx.x;
#pragma unroll
  for (int r = 0; r < 4; ++r) {
    int k = t + r * 256;
    int rk = rank16[g * PP + k];
    const float4* hr = (const float4*)(h + (size_t)(g * PP + k) * IL);
    const float4* pr = (const float4*)(pe + (size_t)rk * IL);
    uint4* orow = (uint4*)(hs + (size_t)(g * PP + k) * IL);
#pragma unroll
    for (int i = 0; i < 12; ++i) {
      float4 a = hr[2 * i], b = hr[2 * i + 1];
      float4 p = pr[2 * i], qq = pr[2 * i + 1];
      __half2 o[4];
      o[0] = __floats2half2_rn(a.x + p.x, a.y + p.y);
      o[1] = __floats2half2_rn(a.z + p.z, a.w + p.w);
      o[2] = __floats2half2_rn(b.x + qq.x, b.y + qq.y);
      o[3] = __floats2half2_rn(b.z + qq.z, b.w + qq.w);
      orow[i] = *(const uint4*)o;
    }
  }
}

// ---------------- capsule k-means routing, one block per graph, 512 threads ----------------
__global__ __launch_bounds__(512) void k_route(const __half* __restrict__ hs,
                                               const float* __restrict__ colsum,
                                               const float* __restrict__ pemean,
                                               const float* __restrict__ capsW,
                                               float* __restrict__ out) {
  __shared__ __half e_l[PP * 12];        // 24 KB  e[k][c] (c<10, pad 12)
  __shared__ float swpart[8][NC * IL];   // 30 KB  per-wave s partials
  __shared__ float u_l[NC * IL];         // 3.75 KB
  __shared__ float s_l[NC * IL];
  __shared__ float v_l[NC * OL];
  __shared__ float nrm_l[NC], gmax_l[NC], gsum_l[NC];
  __shared__ float wred[8][NC];
  int t = threadIdx.x, g = blockIdx.x;
  int lane = t & 63, wvi = t >> 6;
  if (t < IL) s_l[t] = colsum[g * IL + t] * (1.0f / PP) + pemean[t];   // m = mean hs
  __syncthreads();
  if (t < NC * OL) {
    int c = t >> 4, j = t & 15;
    const float* wr = capsW + (size_t)(c * OL + j) * IL;
    float a = 0;
    for (int i = 0; i < IL; ++i) a += wr[i] * s_l[i];
    v_l[t] = a;                                                        // v0 = mean priors
  }
  __syncthreads();
  const __half* hg = hs + (size_t)g * PP * IL;

  for (int it = 0; it < NITER; ++it) {
    if (t < NC) {
      float n2 = 0;
#pragma unroll
      for (int j = 0; j < OL; ++j) { float x = v_l[t * OL + j]; n2 += x * x; }
      nrm_l[t] = 1.0f / (sqrtf(n2) + 1e-12f);
    }
    __syncthreads();
    for (int idx = t; idx < NC * IL; idx += 512) {   // u[c][i] = caps_W^T vn
      int c = idx / IL, i = idx - c * IL;
      const float* wr = capsW + (size_t)c * OL * IL + i;
      float a = 0;
#pragma unroll
      for (int j = 0; j < OL; ++j) a += wr[j * IL] * v_l[c * OL + j];
      u_l[idx] = a * nrm_l[c];
    }
    __syncthreads();
    // ---- logits pass: logits[k][c] = hs[k] . u_c  (rows t and t+512) ----
    float acc[2][NC];
#pragma unroll
    for (int r = 0; r < 2; ++r)
#pragma unroll
      for (int c = 0; c < NC; ++c) acc[r][c] = 0.f;
    for (int i4 = 0; i4 < 12; ++i4) {
      float hv[2][8];
#pragma unroll
      for (int r = 0; r < 2; ++r) {
        int k = t + r * 512;
        uint4 rv = *(const uint4*)(hg + (size_t)k * IL + i4 * 8);
        const __half2* hp = (const __half2*)&rv;
#pragma unroll
        for (int j = 0; j < 4; ++j) {
          float2 f = __half22float2(hp[j]);
          hv[r][2 * j] = f.x; hv[r][2 * j + 1] = f.y;
        }
      }
#pragma unroll
      for (int c = 0; c < NC; ++c) {
        float4 ua = *(const float4*)&u_l[c * IL + i4 * 8];
        float4 ub = *(const float4*)&u_l[c * IL + i4 * 8 + 4];
#pragma unroll
        for (int r = 0; r < 2; ++r)
          acc[r][c] += hv[r][0] * ua.x + hv[r][1] * ua.y + hv[r][2] * ua.z + hv[r][3] * ua.w
                     + hv[r][4] * ub.x + hv[r][5] * ub.y + hv[r][6] * ub.z + hv[r][7] * ub.w;
      }
    }
    // ---- softmax over k ----
    float lmax[NC];
#pragma unroll
    for (int c = 0; c < NC; ++c) lmax[c] = fmaxf(acc[0][c], acc[1][c]);
#pragma unroll
    for (int c = 0; c < NC; ++c)
      for (int m = 32; m >= 1; m >>= 1)
        lmax[c] = fmaxf(lmax[c], __shfl_xor(lmax[c], m, 64));
    if (lane == 0)
#pragma unroll
      for (int c = 0; c < NC; ++c) wred[wvi][c] = lmax[c];
    __syncthreads();
    if (t < NC) {
      float m = wred[0][t];
#pragma unroll
      for (int w = 1; w < 8; ++w) m = fmaxf(m, wred[w][t]);
      gmax_l[t] = m;
    }
    __syncthreads();
    float lsum[NC];
#pragma unroll
    for (int c = 0; c < NC; ++c) lsum[c] = 0.f;
#pragma unroll
    for (int r = 0; r < 2; ++r) {
      int k = t + r * 512;
#pragma unroll
      for (int c = 0; c < NC; ++c) {
        float ev = __expf(acc[r][c] - gmax_l[c]);
        e_l[k * 12 + c] = __float2half(ev);
        lsum[c] += ev;
      }
    }
#pragma unroll
    for (int c = 0; c < NC; ++c)
      for (int m = 32; m >= 1; m >>= 1)
        lsum[c] += __shfl_xor(lsum[c], m, 64);
    if (lane == 0)
#pragma unroll
      for (int c = 0; c < NC; ++c) wred[wvi][c] = lsum[c];
    __syncthreads();
    if (t < NC) {
      float s = 0;
#pragma unroll
      for (int w = 0; w < 8; ++w) s += wred[w][t];
      gsum_l[t] = s;
    }
    __syncthreads();
    // ---- s-pass: s[c][i] = sum_k e[k][c] * hs[k][i]  (64 kstrips x 8 islices of 12) ----
    int isl = t & 7, ks = t >> 3;
    float sl[NC][12];
#pragma unroll
    for (int c = 0; c < NC; ++c)
#pragma unroll
      for (int d = 0; d < 12; ++d) sl[c][d] = 0.f;
    for (int kk = 0; kk < 16; ++kk) {
      int k = ks + 64 * kk;
      const __half* hr = hg + (size_t)k * IL + isl * 12;
      float hv2[12];
#pragma unroll
      for (int qq = 0; qq < 3; ++qq) {
        uint2 rv = *(const uint2*)(hr + qq * 4);
        const __half2* hp = (const __half2*)&rv;
        float2 f0 = __half22float2(hp[0]);
        float2 f1 = __half22float2(hp[1]);
        hv2[qq * 4 + 0] = f0.x; hv2[qq * 4 + 1] = f0.y;
        hv2[qq * 4 + 2] = f1.x; hv2[qq * 4 + 3] = f1.y;
      }
      const __half2* ep = (const __half2*)&e_l[k * 12];
      float ev[NC];
#pragma unroll
      for (int j = 0; j < 5; ++j) {
        float2 f = __half22float2(ep[j]);
        ev[2 * j] = f.x; ev[2 * j + 1] = f.y;
      }
#pragma unroll
      for (int c = 0; c < NC; ++c)
#pragma unroll
        for (int d = 0; d < 12; ++d)
          sl[c][d] += ev[c] * hv2[d];
    }
#pragma unroll
    for (int c = 0; c < NC; ++c)
#pragma unroll
      for (int d = 0; d < 12; ++d) {
        float x = sl[c][d];
        x += __shfl_xor(x, 8, 64);
        x += __shfl_xor(x, 16, 64);
        x += __shfl_xor(x, 32, 64);
        sl[c][d] = x;
      }
    if (lane < 8) {     // lane == isl for this group
#pragma unroll
      for (int c = 0; c < NC; ++c)
#pragma unroll
        for (int d = 0; d < 12; ++d)
          swpart[wvi][c * IL + lane * 12 + d] = sl[c][d];
    }
    __syncthreads();
    for (int idx = t; idx < NC * IL; idx += 512) {
      float a = 0;
#pragma unroll
      for (int w = 0; w < 8; ++w) a += swpart[w][idx];
      s_l[idx] = a;
    }
    __syncthreads();
    // ---- v = caps_W @ s / sumexp ----
    if (t < NC * OL) {
      int c = t >> 4, j = t & 15;
      const float* wr = capsW + (size_t)(c * OL + j) * IL;
      float a = 0;
      for (int i = 0; i < IL; ++i) a += wr[i] * s_l[c * IL + i];
      v_l[t] = a / gsum_l[c];
    }
    __syncthreads();
  }
  if (t < NC) {
    float n2 = 0;
#pragma unroll
    for (int j = 0; j < OL; ++j) { float x = v_l[t * OL + j]; n2 += x * x; }
    out[g * NC + t] = (n2 / (1.0f + n2)) * sqrtf(n2) / sqrtf(n2 + 1e-12f);
  }
}

extern "C" void kernel_launch(void* const* d_in, const int* in_sizes, int n_in,
                              void* d_out, int out_size, void* d_ws, size_t ws_size,
                              hipStream_t stream) {
  const float* x     = (const float*)d_in[0];
  const int*   ei    = (const int*)d_in[1];
  const float* W1    = (const float*)d_in[3];
  const float* b1    = (const float*)d_in[4];
  const float* W2    = (const float*)d_in[5];
  const float* b2    = (const float*)d_in[6];
  const float* W3    = (const float*)d_in[7];
  const float* b3    = (const float*)d_in[8];
  const float* capsW = (const float*)d_in[9];
  float* out = (float*)d_out;

  char* wp = (char*)d_ws;
  auto alloc = [&](size_t bytes) { char* p = wp; wp += (bytes + 255) & ~(size_t)255; return p; };
  float*    dis    = (float*)alloc((size_t)N_NODES * 4);
  float*    h      = (float*)alloc((size_t)N_NODES * IL * 4);
  // --- union region: hlin/epack/esrc16 are dead by the time hs is written ---
  char*     ureg   = wp;
  float*    hlin   = (float*)alloc((size_t)N_NODES * HH * 4);       // 32 MB
  unsigned* epack  = (unsigned*)alloc((size_t)NE * 4);              // 16 MB
  unsigned short* esrc16 = (unsigned short*)alloc((size_t)NG * ECAP * 2); // 9 MB
  __half*   hs     = (__half*)ureg;                                 // 48 MB alias
  unsigned* hist   = (unsigned*)alloc((size_t)NCHUNK * NG * 4);
  unsigned* cbase  = (unsigned*)alloc((size_t)NCHUNK * NG * 4);
  unsigned* gbase  = (unsigned*)alloc((size_t)(NG + 1) * 4);
  unsigned* dstptr = (unsigned*)alloc((size_t)NG * (PP + 1) * 4);
  unsigned short* rank16 = (unsigned short*)alloc((size_t)NG * PP * 2);
  float*    colsum = (float*)alloc((size_t)NG * IL * 4);
  float*    pe     = (float*)alloc((size_t)PP * IL * 4);
  float*    pemean = (float*)alloc((size_t)IL * 4);

  hipMemsetAsync(colsum, 0, (size_t)NG * IL * 4, stream);
  k_hist<<<NCHUNK, 256, 0, stream>>>(ei, hist);
  k_scan<<<1, 256, 0, stream>>>(hist, cbase, gbase);
  k_scatter<<<NCHUNK, 256, 0, stream>>>(ei, cbase, epack);
  k_dstsort<<<NG, 256, 0, stream>>>(epack, gbase, esrc16, dstptr);
  k_dis<<<N_NODES / 256, 256, 0, stream>>>(dstptr, dis);
  k_pe<<<(PP * 48) / 256, 256, 0, stream>>>(pe);
  k_pemean<<<1, 128, 0, stream>>>(pe, pemean);

  k_gemm<<<N_NODES / 512, 256, 0, stream>>>(x, FIN, FIN, W1, hlin);
  k_agg<<<NG * 4, 256, 0, stream>>>(hlin, dis, esrc16, dstptr, b1, 0, h, colsum);
  k_gemm<<<N_NODES / 512, 256, 0, stream>>>(h, IL, HH, W2, hlin);
  k_agg<<<NG * 4, 256, 0, stream>>>(hlin, dis, esrc16, dstptr, b2, 32, h, colsum);
  k_gemm<<<N_NODES / 512, 256, 0, stream>>>(h + 32, IL, HH, W3, hlin);
  k_agg<<<NG * 4, 256, 0, stream>>>(hlin, dis, esrc16, dstptr, b3, 64, h, colsum);

  k_sort<<<NG, 256, 0, stream>>>(h, rank16);
  k_mkhs<<<NG, 256, 0, stream>>>(h, pe, rank16, hs);   // hs aliases hlin/epack/esrc16 (all dead)
  k_route<<<NG, 512, 0, stream>>>(hs, colsum, pemean, capsW, out);
}

// Round 5
// 780.532 us; speedup vs baseline: 4.2065x; 1.2249x over previous
//
#include <hip/hip_runtime.h>
#include <hip/hip_fp16.h>
#include <cstdint>
#include <cstddef>

#define N_NODES   262144
#define NG        256
#define PP        1024
#define NE        4194304
#define FIN       128
#define HH        32
#define NC        10
#define OL        16
#define IL        96
#define NITER     3
#define ECHUNK    4096
#define NCHUNK    (NE/ECHUNK)   // 1024
#define ECAP      18432

typedef _Float16 half8 __attribute__((ext_vector_type(8)));
typedef float f32x4 __attribute__((ext_vector_type(4)));

// ---------------- per-chunk per-graph edge histogram (transposed output) ----------------
__global__ void k_hist(const int* __restrict__ ei, unsigned* __restrict__ histT) {
  __shared__ unsigned lh[NG];
  int t = threadIdx.x, b = blockIdx.x;
  lh[t] = 0;
  __syncthreads();
  int base = b * ECHUNK;
  for (int q = t; q < ECHUNK; q += 256) {
    int e = base + q;
    int s = ei[e], d = ei[NE + e];
    if (s != d) atomicAdd(&lh[s >> 10], 1u);
  }
  __syncthreads();
  histT[t * NCHUNK + b] = lh[t];   // [g][ch]
}

// ---------------- per-graph scan over chunks: cbaseT[ch][g] (within-graph excl), gtot[g] ---
__global__ void k_scanA(const unsigned* __restrict__ histT, unsigned* __restrict__ cbaseT,
                        unsigned* __restrict__ gtot) {
  __shared__ unsigned wtot[4];
  int t = threadIdx.x, g = blockIdx.x;
  int lane = t & 63, wv = t >> 6;
  uint4 hv = *(const uint4*)(histT + (size_t)g * NCHUNK + t * 4);
  unsigned s0 = hv.x, s1 = s0 + hv.y, s2 = s1 + hv.z, s3 = s2 + hv.w;
  unsigned tsum = s3, sc = tsum;
  for (int d = 1; d < 64; d <<= 1) {
    unsigned v = __shfl_up(sc, d, 64);
    if (lane >= d) sc += v;
  }
  if (lane == 63) wtot[wv] = sc;
  __syncthreads();
  unsigned woff = 0;
  for (int w = 0; w < wv; ++w) woff += wtot[w];
  unsigned base = woff + sc - tsum;   // exclusive
  cbaseT[(size_t)(t * 4 + 0) * NG + g] = base;
  cbaseT[(size_t)(t * 4 + 1) * NG + g] = base + s0;
  cbaseT[(size_t)(t * 4 + 2) * NG + g] = base + s1;
  cbaseT[(size_t)(t * 4 + 3) * NG + g] = base + s2;
  if (t == 255) gtot[g] = woff + sc;
}

// ---------------- scan of per-graph totals -> gbase[257] ----------------
__global__ void k_scanB(const unsigned* __restrict__ gtot, unsigned* __restrict__ gbase) {
  __shared__ unsigned wtot[4];
  int t = threadIdx.x;
  int lane = t & 63, wv = t >> 6;
  unsigned x = gtot[t], sc = x;
  for (int d = 1; d < 64; d <<= 1) {
    unsigned v = __shfl_up(sc, d, 64);
    if (lane >= d) sc += v;
  }
  if (lane == 63) wtot[wv] = sc;
  __syncthreads();
  unsigned woff = 0;
  for (int w = 0; w < wv; ++w) woff += wtot[w];
  gbase[t] = woff + sc - x;
  if (t == 255) gbase[256] = woff + sc;
}

// ---------------- scatter edges into graph buckets ----------------
__global__ void k_scatter(const int* __restrict__ ei, const unsigned* __restrict__ cbaseT,
                          const unsigned* __restrict__ gbase, unsigned* __restrict__ epack) {
  __shared__ unsigned lcur[NG];
  int t = threadIdx.x, b = blockIdx.x;
  lcur[t] = gbase[t] + cbaseT[(size_t)b * NG + t];
  __syncthreads();
  int base = b * ECHUNK;
  for (int q = t; q < ECHUNK; q += 256) {
    int e = base + q;
    int s = ei[e], d = ei[NE + e];
    if (s != d) {
      int g = s >> 10;
      unsigned pos = atomicAdd(&lcur[g], 1u);
      epack[pos] = (unsigned)(s & 1023) | ((unsigned)(d & 1023) << 10);
    }
  }
}

// ---------------- per-graph counting sort by dst offset -> CSR + u16 src list ------------
__global__ __launch_bounds__(256) void k_dstsort(const unsigned* __restrict__ epack,
                          const unsigned* __restrict__ gbase,
                          unsigned short* __restrict__ esrc16,
                          unsigned* __restrict__ dstptr) {
  __shared__ unsigned shist[PP];
  __shared__ unsigned wsum[256];
  __shared__ unsigned cur[PP];
  int t = threadIdx.x, g = blockIdx.x;
  unsigned e0 = gbase[g], e1 = gbase[g + 1];
  for (int i = t; i < PP; i += 256) shist[i] = 0;
  __syncthreads();
  for (unsigned e = e0 + t; e < e1; e += 256)
    atomicAdd(&shist[(epack[e] >> 10) & 1023], 1u);
  __syncthreads();
  unsigned h0 = shist[4 * t], h1 = shist[4 * t + 1], h2 = shist[4 * t + 2], h3 = shist[4 * t + 3];
  unsigned tsum = h0 + h1 + h2 + h3;
  wsum[t] = tsum;
  __syncthreads();
  for (int off = 1; off < 256; off <<= 1) {
    unsigned v = (t >= off) ? wsum[t - off] : 0u;
    __syncthreads();
    wsum[t] += v;
    __syncthreads();
  }
  unsigned excl = wsum[t] - tsum;
  unsigned c0 = excl, c1 = c0 + h0, c2 = c1 + h1, c3 = c2 + h2;
  cur[4 * t] = c0; cur[4 * t + 1] = c1; cur[4 * t + 2] = c2; cur[4 * t + 3] = c3;
  unsigned* dp = dstptr + (size_t)g * (PP + 1);
  dp[4 * t] = c0; dp[4 * t + 1] = c1; dp[4 * t + 2] = c2; dp[4 * t + 3] = c3;
  if (t == 0) dp[PP] = e1 - e0;
  __syncthreads();
  unsigned short* eg = esrc16 + (size_t)g * ECAP;
  for (unsigned e = e0 + t; e < e1; e += 256) {
    unsigned pk = epack[e];
    unsigned so = pk & 1023, dofs = (pk >> 10) & 1023;
    unsigned pos = atomicAdd(&cur[dofs], 1u);
    if (pos < ECAP) eg[pos] = (unsigned short)so;
  }
}

// ---------------- dis from CSR degrees ----------------
__global__ void k_dis(const unsigned* __restrict__ dstptr, float* __restrict__ dis) {
  int n = blockIdx.x * 256 + threadIdx.x;
  int g = n >> 10, k = n & 1023;
  const unsigned* dp = dstptr + (size_t)g * (PP + 1) + k;
  float deg = (float)(dp[1] - dp[0]);
  dis[n] = 1.0f / sqrtf(deg + 1.0f);
}

// ---------------- fp32 GEMM: out(N x 32) = xin(N x K, row stride ldx) @ W(K x 32) ----------------
__global__ __launch_bounds__(256) void k_gemm(const float* __restrict__ xin, int ldx, int K,
                                              const float* __restrict__ W,
                                              float* __restrict__ out) {
  __shared__ float Wt[32 * (FIN + 4)];
  int t = threadIdx.x, b = blockIdx.x;
  int stride = K + 4;
  for (int idx = t; idx < K * 32; idx += 256) {
    int k = idx >> 5, c = idx & 31;
    Wt[c * stride + k] = W[idx];
  }
  __syncthreads();
  int cg = t & 3, ng = t >> 2;
  int row0 = b * 512 + ng * 8;
  float acc[8][8];
#pragma unroll
  for (int r = 0; r < 8; ++r)
#pragma unroll
    for (int j = 0; j < 8; ++j) acc[r][j] = 0.f;
  for (int k4 = 0; k4 < (K >> 2); ++k4) {
    float4 xv[8];
#pragma unroll
    for (int r = 0; r < 8; ++r)
      xv[r] = *(const float4*)(xin + (size_t)(row0 + r) * ldx + k4 * 4);
    float4 wvv[8];
#pragma unroll
    for (int j = 0; j < 8; ++j)
      wvv[j] = *(const float4*)&Wt[(cg + 4 * j) * stride + k4 * 4];
#pragma unroll
    for (int j = 0; j < 8; ++j)
#pragma unroll
      for (int r = 0; r < 8; ++r)
        acc[r][j] += xv[r].x * wvv[j].x + xv[r].y * wvv[j].y + xv[r].z * wvv[j].z + xv[r].w * wvv[j].w;
  }
#pragma unroll
  for (int r = 0; r < 8; ++r)
#pragma unroll
    for (int j = 0; j < 8; ++j)
      out[(size_t)(row0 + r) * HH + cg + 4 * j] = acc[r][j];
}

// ---------------- aggregation: dst-owned register accumulation, no atomics ----------------
__global__ __launch_bounds__(256) void k_agg(const float* __restrict__ hlin,
                                             const float* __restrict__ dis,
                                             const unsigned short* __restrict__ esrc16,
                                             const unsigned* __restrict__ dstptr,
                                             const float* __restrict__ bias,
                                             int coloff,
                                             float* __restrict__ h) {
  __shared__ float hsl[PP * 8];
  __shared__ uint4 elv4[ECAP / 8];
  const unsigned short* el = (const unsigned short*)elv4;
  int t = threadIdx.x;
  int g = blockIdx.x >> 2, q = blockIdx.x & 3;
  int c0 = q * 8;
  const unsigned* dp = dstptr + (size_t)g * (PP + 1);
  unsigned cnt = dp[PP];
  float dv[4];
  unsigned p0[4], p1[4];
#pragma unroll
  for (int r = 0; r < 4; ++r) {
    int k = t + r * 256;
    float d = dis[g * PP + k];
    dv[r] = d;
    const float* row = hlin + (size_t)(g * PP + k) * HH + c0;
    float4 a = *(const float4*)row;
    float4 b2 = *(const float4*)(row + 4);
    float* o = &hsl[k * 8];
    o[0] = a.x * d; o[1] = a.y * d; o[2] = a.z * d; o[3] = a.w * d;
    o[4] = b2.x * d; o[5] = b2.y * d; o[6] = b2.z * d; o[7] = b2.w * d;
    p0[r] = dp[k]; p1[r] = dp[k + 1];
  }
  const uint4* egv = (const uint4*)(esrc16 + (size_t)g * ECAP);
  int nv = (int)((cnt + 7) >> 3);
  for (int i = t; i < nv; i += 256) elv4[i] = egv[i];
  __syncthreads();
  float bl[8];
#pragma unroll
  for (int c = 0; c < 8; ++c) bl[c] = bias[c0 + c];
#pragma unroll
  for (int r = 0; r < 4; ++r) {
    int k = t + r * 256;
    float acc[8];
    const float* selfp = &hsl[k * 8];
#pragma unroll
    for (int c = 0; c < 8; ++c) acc[c] = selfp[c];
    unsigned e = p0[r], eend = p1[r];
    for (; e + 1 < eend; e += 2) {
      unsigned so0 = el[e], so1 = el[e + 1];
      const float* s0 = &hsl[so0 * 8];
      const float* s1 = &hsl[so1 * 8];
      float4 a0 = *(const float4*)s0;
      float4 b0 = *(const float4*)(s0 + 4);
      float4 a1 = *(const float4*)s1;
      float4 b1 = *(const float4*)(s1 + 4);
      acc[0] += a0.x + a1.x; acc[1] += a0.y + a1.y;
      acc[2] += a0.z + a1.z; acc[3] += a0.w + a1.w;
      acc[4] += b0.x + b1.x; acc[5] += b0.y + b1.y;
      acc[6] += b0.z + b1.z; acc[7] += b0.w + b1.w;
    }
    if (e < eend) {
      unsigned so0 = el[e];
      const float* s0 = &hsl[so0 * 8];
      float4 a0 = *(const float4*)s0;
      float4 b0 = *(const float4*)(s0 + 4);
      acc[0] += a0.x; acc[1] += a0.y; acc[2] += a0.z; acc[3] += a0.w;
      acc[4] += b0.x; acc[5] += b0.y; acc[6] += b0.z; acc[7] += b0.w;
    }
    float* orow = h + (size_t)(g * PP + k) * IL + coloff + c0;
#pragma unroll
    for (int c = 0; c < 8; ++c)
      orow[c] = tanhf(dv[r] * acc[c] + bl[c]);
  }
}

// ---------------- per-graph stable descending sort by last channel (bitonic) ----------------
__global__ void k_sort(const float* __restrict__ h, unsigned short* __restrict__ rank16) {
  __shared__ float key[PP];
  __shared__ unsigned sidx[PP];
  int t = threadIdx.x, g = blockIdx.x;
  for (int i = t; i < PP; i += 256) {
    key[i] = h[(size_t)(g * PP + i) * IL + (IL - 1)];
    sidx[i] = i;
  }
  __syncthreads();
  for (int sz = 2; sz <= PP; sz <<= 1) {
    for (int st = sz >> 1; st > 0; st >>= 1) {
      for (int q = t; q < PP / 2; q += 256) {
        int i = 2 * q - (q & (st - 1));
        int j = i + st;
        float ki = key[i], kj = key[j];
        unsigned ii = sidx[i], ij = sidx[j];
        bool less_ji = (kj > ki) || (kj == ki && ij < ii);
        bool asc = ((i & sz) == 0);
        if (less_ji == asc) { key[i] = kj; key[j] = ki; sidx[i] = ij; sidx[j] = ii; }
      }
      __syncthreads();
    }
  }
  for (int i = t; i < PP; i += 256) rank16[g * PP + sidx[i]] = (unsigned short)i;
}

// ---------------- position encoding ----------------
__global__ void k_pe(float* __restrict__ pe) {
  int id = blockIdx.x * 256 + threadIdx.x;
  if (id >= PP * 48) return;
  int pos = id / 48, i = id % 48;
  float denom = powf(10000.0f, (2.0f * i) / 96.0f);
  float ang = (float)pos / denom;
  pe[pos * IL + 2 * i] = sinf(ang);
  pe[pos * IL + 2 * i + 1] = cosf(ang);
}

// ---------------- WPE[c][pos][j] = sum_i capsW[c][j][i] * pe[pos][i], fp16 ----------------
__global__ void k_wpe(const float* __restrict__ pe, const float* __restrict__ capsW,
                      __half* __restrict__ wpe) {
  int id = blockIdx.x * 256 + threadIdx.x;
  if (id >= NC * PP * OL) return;
  int j = id & 15;
  int pos = (id >> 4) & 1023;
  int c = id >> 14;
  const float* wr = capsW + (size_t)(c * OL + j) * IL;
  const float* pr = pe + (size_t)pos * IL;
  float a = 0;
#pragma unroll 8
  for (int i = 0; i < IL; ++i) a += wr[i] * pr[i];
  wpe[(((size_t)c << 10) + pos) * 16 + j] = __float2half(a);
}

// ---------------- priors GEMM via MFMA f16: Pc[g][c][k][16] = h[k] @ capsW[c*16+j] ---------
// A: h rows fp32 -> f16 frags; B: capsW rows fp32 -> f16 frags; D fp32 -> fp16 store.
// 16x16x32 f16 layout (verified): A[m=lane&15][k=(lane>>4)*8+j]; B[k][n=lane&15];
// C/D: col=lane&15, row=(lane>>4)*4+reg.
__global__ __launch_bounds__(256) void k_pgemm(const float* __restrict__ h,
                                               const float* __restrict__ capsW,
                                               __half* __restrict__ Pc) {
  int t = threadIdx.x, b = blockIdx.x;
  int g = b >> 2;
  int wv = t >> 6, lane = t & 63;
  int quad = lane >> 4, l16 = lane & 15;
  half8 afr[4][3];
#pragma unroll
  for (int rt = 0; rt < 4; ++rt) {
    int row = b * 256 + wv * 64 + rt * 16 + l16;
    const float* hr = h + (size_t)row * IL + quad * 8;
#pragma unroll
    for (int kb = 0; kb < 3; ++kb) {
      float4 x = *(const float4*)(hr + kb * 32);
      float4 y = *(const float4*)(hr + kb * 32 + 4);
      half8 a;
      a[0] = (_Float16)x.x; a[1] = (_Float16)x.y; a[2] = (_Float16)x.z; a[3] = (_Float16)x.w;
      a[4] = (_Float16)y.x; a[5] = (_Float16)y.y; a[6] = (_Float16)y.z; a[7] = (_Float16)y.w;
      afr[rt][kb] = a;
    }
  }
  int krow_base = (b & 3) * 256 + wv * 64;
  for (int ct = 0; ct < NC; ++ct) {
    half8 bfr[3];
    const float* wr = capsW + (size_t)(ct * 16 + l16) * IL + quad * 8;
#pragma unroll
    for (int kb = 0; kb < 3; ++kb) {
      float4 x = *(const float4*)(wr + kb * 32);
      float4 y = *(const float4*)(wr + kb * 32 + 4);
      half8 bb;
      bb[0] = (_Float16)x.x; bb[1] = (_Float16)x.y; bb[2] = (_Float16)x.z; bb[3] = (_Float16)x.w;
      bb[4] = (_Float16)y.x; bb[5] = (_Float16)y.y; bb[6] = (_Float16)y.z; bb[7] = (_Float16)y.w;
      bfr[kb] = bb;
    }
#pragma unroll
    for (int rt = 0; rt < 4; ++rt) {
      f32x4 acc = {0.f, 0.f, 0.f, 0.f};
      acc = __builtin_amdgcn_mfma_f32_16x16x32_f16(afr[rt][0], bfr[0], acc, 0, 0, 0);
      acc = __builtin_amdgcn_mfma_f32_16x16x32_f16(afr[rt][1], bfr[1], acc, 0, 0, 0);
      acc = __builtin_amdgcn_mfma_f32_16x16x32_f16(afr[rt][2], bfr[2], acc, 0, 0, 0);
      int krow = krow_base + rt * 16;
      __half* po = Pc + ((((size_t)g * NC + ct) << 10) + krow) * 16 + l16;
#pragma unroll
      for (int r = 0; r < 4; ++r)
        po[(quad * 4 + r) * 16] = __float2half(acc[r]);
    }
  }
}

// ---------------- routing: one block per (graph, capsule), P rows in registers ----------------
__global__ __launch_bounds__(256) void k_route2(const __half* __restrict__ Pc,
                                                const __half* __restrict__ wpe,
                                                const unsigned short* __restrict__ rank16,
                                                float* __restrict__ out) {
  __shared__ float v_l[16];
  __shared__ float wred[4][17];
  int t = threadIdx.x;
  int gc = blockIdx.x;
  int g = gc / NC, c = gc - g * NC;
  int lane = t & 63, wv = t >> 6;
  const __half* pg = Pc + ((size_t)gc << 10) * 16;
  const unsigned short* rk = rank16 + (size_t)g * PP;
  const __half* wc = wpe + ((size_t)c << 10) * 16;
  float pr[4][16];
  float vsum[16];
#pragma unroll
  for (int i = 0; i < 16; ++i) vsum[i] = 0.f;
#pragma unroll
  for (int r = 0; r < 4; ++r) {
    int k = t + r * 256;
    uint4 a0 = *(const uint4*)(pg + (size_t)k * 16);
    uint4 a1 = *(const uint4*)(pg + (size_t)k * 16 + 8);
    int rkk = rk[k];
    uint4 b0 = *(const uint4*)(wc + (size_t)rkk * 16);
    uint4 b1 = *(const uint4*)(wc + (size_t)rkk * 16 + 8);
    const __half2* pa0 = (const __half2*)&a0; const __half2* pa1 = (const __half2*)&a1;
    const __half2* pb0 = (const __half2*)&b0; const __half2* pb1 = (const __half2*)&b1;
#pragma unroll
    for (int j = 0; j < 4; ++j) {
      float2 fa = __half22float2(pa0[j]); float2 fb = __half22float2(pb0[j]);
      pr[r][2 * j] = fa.x + fb.x; pr[r][2 * j + 1] = fa.y + fb.y;
      float2 fa1 = __half22float2(pa1[j]); float2 fb1 = __half22float2(pb1[j]);
      pr[r][8 + 2 * j] = fa1.x + fb1.x; pr[r][8 + 2 * j + 1] = fa1.y + fb1.y;
    }
#pragma unroll
    for (int i = 0; i < 16; ++i) vsum[i] += pr[r][i];
  }
#pragma unroll
  for (int d = 1; d < 64; d <<= 1)
#pragma unroll
    for (int i = 0; i < 16; ++i) vsum[i] += __shfl_xor(vsum[i], d, 64);
  if (lane == 0) {
#pragma unroll
    for (int i = 0; i < 16; ++i) wred[wv][i] = vsum[i];
  }
  __syncthreads();
  if (t < 16) v_l[t] = wred[0][t] + wred[1][t] + wred[2][t] + wred[3][t];
  __syncthreads();
  for (int it = 0; it < NITER; ++it) {
    float vn[16]; float n2 = 0;
#pragma unroll
    for (int i = 0; i < 16; ++i) { float x = v_l[i]; vn[i] = x; n2 += x * x; }
    float inv = 1.0f / (sqrtf(n2) + 1e-12f);
#pragma unroll
    for (int i = 0; i < 16; ++i) vn[i] *= inv;
    float lg[4];
#pragma unroll
    for (int r = 0; r < 4; ++r) {
      float a = 0;
#pragma unroll
      for (int i = 0; i < 16; ++i) a += pr[r][i] * vn[i];
      lg[r] = a;
    }
    float mx = fmaxf(fmaxf(lg[0], lg[1]), fmaxf(lg[2], lg[3]));
#pragma unroll
    for (int d = 1; d < 64; d <<= 1) mx = fmaxf(mx, __shfl_xor(mx, d, 64));
    __syncthreads();   // wred safe to rewrite
    if (lane == 0) wred[wv][16] = mx;
    __syncthreads();
    float gmax = fmaxf(fmaxf(wred[0][16], wred[1][16]), fmaxf(wred[2][16], wred[3][16]));
    float es = 0; float eacc[16];
#pragma unroll
    for (int i = 0; i < 16; ++i) eacc[i] = 0.f;
#pragma unroll
    for (int r = 0; r < 4; ++r) {
      float e = __expf(lg[r] - gmax);
      es += e;
#pragma unroll
      for (int i = 0; i < 16; ++i) eacc[i] += e * pr[r][i];
    }
#pragma unroll
    for (int d = 1; d < 64; d <<= 1) {
      es += __shfl_xor(es, d, 64);
#pragma unroll
      for (int i = 0; i < 16; ++i) eacc[i] += __shfl_xor(eacc[i], d, 64);
    }
    __syncthreads();   // gmax consumed by all waves
    if (lane == 0) {
#pragma unroll
      for (int i = 0; i < 16; ++i) wred[wv][i] = eacc[i];
      wred[wv][16] = es;
    }
    __syncthreads();
    if (t < 16) {
      float s = wred[0][t] + wred[1][t] + wred[2][t] + wred[3][t];
      float S = wred[0][16] + wred[1][16] + wred[2][16] + wred[3][16];
      v_l[t] = s / S;
    }
    __syncthreads();
  }
  if (t == 0) {
    float n2 = 0;
#pragma unroll
    for (int i = 0; i < 16; ++i) { float x = v_l[i]; n2 += x * x; }
    out[gc] = (n2 / (1.0f + n2)) * sqrtf(n2) / sqrtf(n2 + 1e-12f);
  }
}

extern "C" void kernel_launch(void* const* d_in, const int* in_sizes, int n_in,
                              void* d_out, int out_size, void* d_ws, size_t ws_size,
                              hipStream_t stream) {
  const float* x     = (const float*)d_in[0];
  const int*   ei    = (const int*)d_in[1];
  const float* W1    = (const float*)d_in[3];
  const float* b1    = (const float*)d_in[4];
  const float* W2    = (const float*)d_in[5];
  const float* b2    = (const float*)d_in[6];
  const float* W3    = (const float*)d_in[7];
  const float* b3    = (const float*)d_in[8];
  const float* capsW = (const float*)d_in[9];
  float* out = (float*)d_out;

  char* wp = (char*)d_ws;
  auto alloc = [&](size_t bytes) { char* p = wp; wp += (bytes + 255) & ~(size_t)255; return p; };
  float*    dis    = (float*)alloc((size_t)N_NODES * 4);
  float*    h      = (float*)alloc((size_t)N_NODES * IL * 4);
  // --- union region: hlin/epack/esrc16/histT/cbaseT dead before Pc is written ---
  char*     ureg   = wp;
  float*    hlin   = (float*)alloc((size_t)N_NODES * HH * 4);            // 32 MB
  unsigned* epack  = (unsigned*)alloc((size_t)NE * 4);                   // 16 MB
  unsigned short* esrc16 = (unsigned short*)alloc((size_t)NG * ECAP * 2);// 9 MB
  unsigned* histT  = (unsigned*)alloc((size_t)NCHUNK * NG * 4);          // 1 MB
  unsigned* cbaseT = (unsigned*)alloc((size_t)NCHUNK * NG * 4);          // 1 MB
  const size_t PC_BYTES = (size_t)NG * NC * PP * 16 * 2;                 // 80 MiB
  if ((size_t)(wp - ureg) < PC_BYTES) wp = ureg + ((PC_BYTES + 255) & ~(size_t)255);
  __half*   Pc     = (__half*)ureg;                                      // aliases union
  unsigned* gtot   = (unsigned*)alloc((size_t)NG * 4);
  unsigned* gbase  = (unsigned*)alloc((size_t)(NG + 1) * 4);
  unsigned* dstptr = (unsigned*)alloc((size_t)NG * (PP + 1) * 4);
  unsigned short* rank16 = (unsigned short*)alloc((size_t)NG * PP * 2);
  float*    pe     = (float*)alloc((size_t)PP * IL * 4);
  __half*   wpe    = (__half*)alloc((size_t)NC * PP * OL * 2);

  k_hist<<<NCHUNK, 256, 0, stream>>>(ei, histT);
  k_scanA<<<NG, 256, 0, stream>>>(histT, cbaseT, gtot);
  k_scanB<<<1, 256, 0, stream>>>(gtot, gbase);
  k_scatter<<<NCHUNK, 256, 0, stream>>>(ei, cbaseT, gbase, epack);
  k_dstsort<<<NG, 256, 0, stream>>>(epack, gbase, esrc16, dstptr);
  k_dis<<<N_NODES / 256, 256, 0, stream>>>(dstptr, dis);
  k_pe<<<(PP * 48) / 256, 256, 0, stream>>>(pe);
  k_wpe<<<(NC * PP * OL) / 256, 256, 0, stream>>>(pe, capsW, wpe);

  k_gemm<<<N_NODES / 512, 256, 0, stream>>>(x, FIN, FIN, W1, hlin);
  k_agg<<<NG * 4, 256, 0, stream>>>(hlin, dis, esrc16, dstptr, b1, 0, h);
  k_gemm<<<N_NODES / 512, 256, 0, stream>>>(h, IL, HH, W2, hlin);
  k_agg<<<NG * 4, 256, 0, stream>>>(hlin, dis, esrc16, dstptr, b2, 32, h);
  k_gemm<<<N_NODES / 512, 256, 0, stream>>>(h + 32, IL, HH, W3, hlin);
  k_agg<<<NG * 4, 256, 0, stream>>>(hlin, dis, esrc16, dstptr, b3, 64, h);

  k_sort<<<NG, 256, 0, stream>>>(h, rank16);
  k_pgemm<<<N_NODES / 256, 256, 0, stream>>>(h, capsW, Pc);   // Pc overlays dead buffers
  k_route2<<<NG * NC, 256, 0, stream>>>(Pc, wpe, rank16, out);
}